// Round 1
// 2586.813 us; speedup vs baseline: 1.0606x; 1.0606x over previous
//
#include <hip/hip_runtime.h>
#include <cmath>

#define SEQLEN 8
#define CH 64  // IN_CH == HID == 64

typedef unsigned short ushort_t;

__device__ __forceinline__ ushort_t f2bf(float f) {
  union { float f; unsigned u; } v; v.f = f;
  unsigned r = v.u + 0x7fff + ((v.u >> 16) & 1);  // round-nearest-even
  return (ushort_t)(r >> 16);
}
__device__ __forceinline__ float bf2f(ushort_t h) {
  union { unsigned u; float f; } v; v.u = ((unsigned)h) << 16;
  return v.f;
}

// ---- setup: degree + count histogram over rows ----
__global__ __launch_bounds__(256) void edge_hist_kernel(
    const int* __restrict__ ei, const float* __restrict__ ew,
    float* __restrict__ deg, int* __restrict__ cnt, int E) {
  int e = blockIdx.x * 256 + threadIdx.x;
  if (e >= E) return;
  int r = ei[e];
  int c = ei[E + e];
  float wv = (r == c) ? 0.f : ew[e];
  atomicAdd(deg + r, wv);
  atomicAdd(cnt + r, 1);
}

__global__ __launch_bounds__(256) void dinv_kernel(
    const float* __restrict__ deg, float* __restrict__ dinv, int n) {
  int i = blockIdx.x * 256 + threadIdx.x;
  if (i >= n) return;
  float d = deg[i];
  dinv[i] = (d > 0.f) ? (1.0f / sqrtf(d)) : 0.f;
}

// ---- hierarchical scan ----
__global__ __launch_bounds__(256) void scan_part_kernel(
    const int* __restrict__ cnt, int* __restrict__ bsum, int n) {
  int i = blockIdx.x * 256 + threadIdx.x;
  int v = (i < n) ? cnt[i] : 0;
#pragma unroll
  for (int o = 32; o; o >>= 1) v += __shfl_down(v, o, 64);
  __shared__ int red[4];
  if ((threadIdx.x & 63) == 0) red[threadIdx.x >> 6] = v;
  __syncthreads();
  if (threadIdx.x == 0) bsum[blockIdx.x] = red[0] + red[1] + red[2] + red[3];
}

__global__ __launch_bounds__(256) void scan_top_kernel(int* __restrict__ bsum, int nb) {
  int tid = threadIdx.x, lane = tid & 63, wid = tid >> 6;
  int v = (tid < nb) ? bsum[tid] : 0;
  int orig = v;
#pragma unroll
  for (int o = 1; o < 64; o <<= 1) { int t = __shfl_up(v, o, 64); if (lane >= o) v += t; }
  __shared__ int wsum[4];
  if (lane == 63) wsum[wid] = v;
  __syncthreads();
  int base = 0;
  for (int w = 0; w < wid; ++w) base += wsum[w];
  if (tid < nb) bsum[tid] = base + v - orig;
}

__global__ __launch_bounds__(256) void scan_fill_kernel(
    const int* __restrict__ cnt, const int* __restrict__ bsum,
    int* __restrict__ rowp, int* __restrict__ woff, int n, int total) {
  int i = blockIdx.x * 256 + threadIdx.x;
  int tid = threadIdx.x, lane = tid & 63, wid = tid >> 6;
  int v = (i < n) ? cnt[i] : 0;
  int orig = v;
#pragma unroll
  for (int o = 1; o < 64; o <<= 1) { int t = __shfl_up(v, o, 64); if (lane >= o) v += t; }
  __shared__ int wsum[4];
  if (lane == 63) wsum[wid] = v;
  __syncthreads();
  int base = bsum[blockIdx.x];
  for (int w = 0; w < wid; ++w) base += wsum[w];
  if (i < n) { int ex = base + v - orig; rowp[i] = ex; woff[i] = ex; }
  if (blockIdx.x == 0 && tid == 0) rowp[n] = total;
}

__global__ __launch_bounds__(256) void scatter_kernel(
    const int* __restrict__ ei, const float* __restrict__ ew,
    const float* __restrict__ dinv, int* __restrict__ woff,
    int* __restrict__ ccol, float* __restrict__ cwn, int E) {
  int e = blockIdx.x * 256 + threadIdx.x;
  if (e >= E) return;
  int r = ei[e];
  int c = ei[E + e];
  float wv = (r == c) ? 0.f : ew[e];
  float wn = -wv * dinv[r] * dinv[c];
  int pos = atomicAdd(woff + r, 1);
  ccol[pos] = c;
  cwn[pos] = wn;
}

// fp32 -> bf16 bulk convert (for X slabs)
__global__ __launch_bounds__(256) void cvt_bf_kernel(
    const float4* __restrict__ in, ushort_t* __restrict__ outb, long long n4) {
  long long i = (long long)blockIdx.x * 256 + threadIdx.x;
  if (i >= n4) return;
  float4 v = in[i];
  ushort4 o4;
  o4.x = f2bf(v.x); o4.y = f2bf(v.y); o4.z = f2bf(v.z); o4.w = f2bf(v.w);
  *(ushort4*)(outb + (size_t)i * 4) = o4;
}

// ---- SpMV, fp32 payload (fallback tier) ----
__global__ __launch_bounds__(256) void spmv_kernel(
    const int* __restrict__ rowp, const int* __restrict__ ccol,
    const float* __restrict__ cwn, const float* __restrict__ v,
    const float* __restrict__ u, float* __restrict__ y,
    float alpha, float beta, int n, long long slab_stride) {
  int r = blockIdx.x * 4 + (threadIdx.x >> 6);
  if (r >= n) return;
  long long so = (long long)blockIdx.y * slab_stride;
  const float* __restrict__ vs = v + so;
  const float* __restrict__ us = u + so;
  float* __restrict__ ys = y + so;
  int lane = threadIdx.x & 63;
  int s = __builtin_amdgcn_readfirstlane(rowp[r]);
  int e = __builtin_amdgcn_readfirstlane(rowp[r + 1]);
  float a0 = 0.f, a1 = 0.f, a2 = 0.f, a3 = 0.f;
  int i = s;
  for (; i + 4 <= e; i += 4) {
    int c0 = ccol[i], c1 = ccol[i + 1], c2 = ccol[i + 2], c3 = ccol[i + 3];
    float w0 = cwn[i], w1 = cwn[i + 1], w2 = cwn[i + 2], w3 = cwn[i + 3];
    float x0 = vs[(size_t)c0 * CH + lane];
    float x1 = vs[(size_t)c1 * CH + lane];
    float x2 = vs[(size_t)c2 * CH + lane];
    float x3 = vs[(size_t)c3 * CH + lane];
    a0 = fmaf(w0, x0, a0); a1 = fmaf(w1, x1, a1);
    a2 = fmaf(w2, x2, a2); a3 = fmaf(w3, x3, a3);
  }
  for (; i < e; ++i) a0 = fmaf(cwn[i], vs[(size_t)ccol[i] * CH + lane], a0);
  float res = alpha * ((a0 + a1) + (a2 + a3));
  if (beta != 0.f) res += beta * us[(size_t)r * CH + lane];
  ys[(size_t)r * CH + lane] = res;
}

// ---- SpMV, bf16 gather payload (halves gather demand + L2 footprint) ----
// y (fp32) optional; yb (bf16 shadow for subsequent gathers/GEMM-A) optional.
__global__ __launch_bounds__(256) void spmv_bf_kernel(
    const int* __restrict__ rowp, const int* __restrict__ ccol,
    const float* __restrict__ cwn, const ushort_t* __restrict__ v,
    const float* __restrict__ u, float* __restrict__ y, ushort_t* __restrict__ yb,
    float alpha, float beta, int n, long long slab_stride) {
  int r = blockIdx.x * 4 + (threadIdx.x >> 6);
  if (r >= n) return;
  long long so = (long long)blockIdx.y * slab_stride;
  const ushort_t* __restrict__ vs = v + so;
  const float* __restrict__ us = u + so;
  int lane = threadIdx.x & 63;
  int s = __builtin_amdgcn_readfirstlane(rowp[r]);
  int e = __builtin_amdgcn_readfirstlane(rowp[r + 1]);
  float a0 = 0.f, a1 = 0.f, a2 = 0.f, a3 = 0.f;
  int i = s;
  for (; i + 4 <= e; i += 4) {
    int c0 = ccol[i], c1 = ccol[i + 1], c2 = ccol[i + 2], c3 = ccol[i + 3];
    float w0 = cwn[i], w1 = cwn[i + 1], w2 = cwn[i + 2], w3 = cwn[i + 3];
    float x0 = bf2f(vs[(size_t)c0 * CH + lane]);
    float x1 = bf2f(vs[(size_t)c1 * CH + lane]);
    float x2 = bf2f(vs[(size_t)c2 * CH + lane]);
    float x3 = bf2f(vs[(size_t)c3 * CH + lane]);
    a0 = fmaf(w0, x0, a0); a1 = fmaf(w1, x1, a1);
    a2 = fmaf(w2, x2, a2); a3 = fmaf(w3, x3, a3);
  }
  for (; i < e; ++i) a0 = fmaf(cwn[i], bf2f(vs[(size_t)ccol[i] * CH + lane]), a0);
  float res = alpha * ((a0 + a1) + (a2 + a3));
  if (beta != 0.f) res += beta * us[(size_t)r * CH + lane];
  size_t oi = (size_t)r * CH + lane;
  if (y) y[so + oi] = res;
  if (yb) yb[so + oi] = f2bf(res);
}

// ---- fused multi-gate GEMM ----
struct FG {
  const float* A[3];       // fp32 A slab (used when AB[kk] == nullptr)
  const ushort_t* AB[3];   // bf16 A slab (takes precedence)
  const float* W[3];
  const float* Bv[3];
  const float* P[3];
  const float* Hb;
  const float* Zb;
  float* O[3];
  ushort_t* OB0;  // optional bf16 shadow: MODE1 -> of O[1]; MODE2 -> of O[0]
  int n;
  long long tstride;
};

__device__ __forceinline__ void fma_tile(float (&acc)[4][4], const float* At,
                                         const float* Wt, int r0, int c0) {
#pragma unroll 4
  for (int k = 0; k < 64; ++k) {
    float4 a = *(const float4*)(At + k * 68 + r0);
    float4 w = *(const float4*)(Wt + k * 64 + c0);
    float av[4] = { a.x, a.y, a.z, a.w };
    float wv[4] = { w.x, w.y, w.z, w.w };
#pragma unroll
    for (int i = 0; i < 4; ++i)
#pragma unroll
      for (int j = 0; j < 4; ++j)
        acc[i][j] = fmaf(av[i], wv[j], acc[i][j]);
  }
}

__device__ __forceinline__ float sigf(float x) { return 1.f / (1.f + expf(-x)); }

template <int MODE, int G>
__global__ __launch_bounds__(256) void gemmf_kernel(FG p) {
  __shared__ float At[64 * 68];
  __shared__ float Wt[64 * 64];
  const int tid = threadIdx.x;
  const int n0 = blockIdx.x * 64;
  const int r0 = (tid >> 4) << 2;
  const int c0 = (tid & 15) << 2;
  const long long toff = (long long)blockIdx.z * p.tstride;
  float acc[G][4][4];
#pragma unroll
  for (int g = 0; g < G; ++g)
#pragma unroll
    for (int i = 0; i < 4; ++i)
#pragma unroll
      for (int j = 0; j < 4; ++j) acc[g][i][j] = 0.f;

  for (int kk = 0; kk < 3; ++kk) {
    const float* __restrict__ A = p.A[kk] ? (p.A[kk] + toff) : nullptr;
    const ushort_t* __restrict__ Ab = p.AB[kk] ? (p.AB[kk] + toff) : nullptr;
    __syncthreads();
#pragma unroll
    for (int j = 0; j < 4; ++j) {
      int flat = tid + 256 * j;
      int r = flat >> 4;
      int k4 = (flat & 15) << 2;
      int nn = n0 + r;
      float4 av;
      if (nn < p.n) {
        if (Ab) {
          ushort4 uv = *(const ushort4*)(Ab + (size_t)nn * CH + k4);
          av = make_float4(bf2f(uv.x), bf2f(uv.y), bf2f(uv.z), bf2f(uv.w));
        } else {
          av = *(const float4*)(A + (size_t)nn * CH + k4);
        }
      } else {
        av = make_float4(0.f, 0.f, 0.f, 0.f);
      }
      At[(k4 + 0) * 68 + r] = av.x;
      At[(k4 + 1) * 68 + r] = av.y;
      At[(k4 + 2) * 68 + r] = av.z;
      At[(k4 + 3) * 68 + r] = av.w;
    }
#pragma unroll
    for (int g = 0; g < G; ++g) {
      if (g > 0) __syncthreads();
      const float* __restrict__ Wk = p.W[g] + kk * 4096;
#pragma unroll
      for (int j = 0; j < 4; ++j) {
        int flat = tid + 256 * j;
        *(float4*)(Wt + flat * 4) = *(const float4*)(Wk + flat * 4);
      }
      __syncthreads();
      fma_tile(acc[g], At, Wt, r0, c0);
    }
  }

  if (MODE == 0) {
#pragma unroll
    for (int g = 0; g < G; ++g) {
      float4 bv = *(const float4*)(p.Bv[g] + c0);
      float* og = p.O[g] + toff;
#pragma unroll
      for (int i = 0; i < 4; ++i) {
        int nn = n0 + r0 + i;
        if (nn < p.n) {
          float4 o;
          o.x = acc[g][i][0] + bv.x;
          o.y = acc[g][i][1] + bv.y;
          o.z = acc[g][i][2] + bv.z;
          o.w = acc[g][i][3] + bv.w;
          *(float4*)(og + (size_t)nn * CH + c0) = o;
        }
      }
    }
  } else if (MODE == 1) {
    float4 bz = *(const float4*)(p.Bv[0] + c0);
    float4 br = *(const float4*)(p.Bv[1] + c0);
#pragma unroll
    for (int i = 0; i < 4; ++i) {
      int nn = n0 + r0 + i;
      if (nn < p.n) {
        size_t idx = (size_t)nn * CH + c0;
        float4 pz = *(const float4*)(p.P[0] + idx);
        float4 pr = *(const float4*)(p.P[1] + idx);
        float4 h4 = *(const float4*)(p.Hb + idx);
        float4 z, gg;
        z.x = sigf(pz.x + bz.x + acc[0][i][0]);
        z.y = sigf(pz.y + bz.y + acc[0][i][1]);
        z.z = sigf(pz.z + bz.z + acc[0][i][2]);
        z.w = sigf(pz.w + bz.w + acc[0][i][3]);
        gg.x = h4.x * sigf(pr.x + br.x + acc[1][i][0]);
        gg.y = h4.y * sigf(pr.y + br.y + acc[1][i][1]);
        gg.z = h4.z * sigf(pr.z + br.z + acc[1][i][2]);
        gg.w = h4.w * sigf(pr.w + br.w + acc[1][i][3]);
        *(float4*)(p.O[0] + idx) = z;
        *(float4*)(p.O[1] + idx) = gg;
        if (p.OB0) {
          ushort4 ob;
          ob.x = f2bf(gg.x); ob.y = f2bf(gg.y);
          ob.z = f2bf(gg.z); ob.w = f2bf(gg.w);
          *(ushort4*)(p.OB0 + idx) = ob;
        }
      }
    }
  } else {
    float4 bh = *(const float4*)(p.Bv[0] + c0);
#pragma unroll
    for (int i = 0; i < 4; ++i) {
      int nn = n0 + r0 + i;
      if (nn < p.n) {
        size_t idx = (size_t)nn * CH + c0;
        float4 ph = *(const float4*)(p.P[0] + idx);
        float4 z4 = *(const float4*)(p.Zb + idx);
        float4 h4 = *(const float4*)(p.Hb + idx);
        float4 o;
        float t0 = tanhf(ph.x + bh.x + acc[0][i][0]);
        float t1 = tanhf(ph.y + bh.y + acc[0][i][1]);
        float t2 = tanhf(ph.z + bh.z + acc[0][i][2]);
        float t3 = tanhf(ph.w + bh.w + acc[0][i][3]);
        o.x = z4.x * h4.x + (1.f - z4.x) * t0;
        o.y = z4.y * h4.y + (1.f - z4.y) * t1;
        o.z = z4.z * h4.z + (1.f - z4.z) * t2;
        o.w = z4.w * h4.w + (1.f - z4.w) * t3;
        *(float4*)(p.O[0] + idx) = o;
        if (p.OB0) {
          ushort4 ob;
          ob.x = f2bf(o.x); ob.y = f2bf(o.y);
          ob.z = f2bf(o.z); ob.w = f2bf(o.w);
          *(ushort4*)(p.OB0 + idx) = ob;
        }
      }
    }
  }
}

// t=0: H=0 => out0 = (1-sig(xzp+b_hz)) * tanh(xhp+b_hh); also bf16 shadow for step 1
__global__ __launch_bounds__(256) void t0_kernel(
    const float4* __restrict__ xzp, const float4* __restrict__ xhp,
    const float* __restrict__ b_hz, const float* __restrict__ b_hh,
    float4* __restrict__ out0, ushort_t* __restrict__ out0b, int n4) {
  int i = blockIdx.x * 256 + threadIdx.x;
  if (i >= n4) return;
  int cb = (i << 2) & 63;
  float4 bz = *(const float4*)(b_hz + cb);
  float4 bh = *(const float4*)(b_hh + cb);
  float4 z4 = xzp[i], h4 = xhp[i];
  float4 o;
  o.x = (1.f - sigf(z4.x + bz.x)) * tanhf(h4.x + bh.x);
  o.y = (1.f - sigf(z4.y + bz.y)) * tanhf(h4.y + bh.y);
  o.z = (1.f - sigf(z4.z + bz.z)) * tanhf(h4.z + bh.z);
  o.w = (1.f - sigf(z4.w + bz.w)) * tanhf(h4.w + bh.w);
  out0[i] = o;
  if (out0b) {
    ushort4 ob;
    ob.x = f2bf(o.x); ob.y = f2bf(o.y); ob.z = f2bf(o.z); ob.w = f2bf(o.w);
    *(ushort4*)(out0b + (size_t)i * 4) = ob;
  }
}

extern "C" void kernel_launch(void* const* d_in, const int* in_sizes, int n_in,
                              void* d_out, int out_size, void* d_ws, size_t ws_size,
                              hipStream_t stream) {
  const float* X    = (const float*)d_in[0];
  const int*   ei   = (const int*)d_in[1];
  const float* ewt  = (const float*)d_in[2];
  const float* W_xz = (const float*)d_in[3];  const float* b_xz = (const float*)d_in[4];
  const float* W_hz = (const float*)d_in[5];  const float* b_hz = (const float*)d_in[6];
  const float* W_xr = (const float*)d_in[7];  const float* b_xr = (const float*)d_in[8];
  const float* W_hr = (const float*)d_in[9];  const float* b_hr = (const float*)d_in[10];
  const float* W_xh = (const float*)d_in[11]; const float* b_xh = (const float*)d_in[12];
  const float* W_hh = (const float*)d_in[13]; const float* b_hh = (const float*)d_in[14];

  const int N = in_sizes[0] / (SEQLEN * CH);
  const int E = in_sizes[1] / 2;
  const size_t NF = (size_t)N * CH;
  float* out = (float*)d_out;

  char* base = (char*)d_ws;
  size_t off = 0;
  auto take = [&](size_t bytes) -> void* {
    off = (off + 255) & ~(size_t)255;
    void* p = base + off;
    off += bytes;
    return p;
  };
  // --- fp32 core (needed by all tiers): ~97 MB ---
  float* deg   = (float*)take((size_t)N * 4);
  float* dinv  = (float*)take((size_t)N * 4);
  int*   cnt   = (int*)take((size_t)N * 4);
  int*   rowp  = (int*)take((size_t)(N + 1) * 4);
  int*   woff  = (int*)take((size_t)(N + 1) * 4);
  int*   bsum  = (int*)take(1024 * 4);
  int*   ccol  = (int*)take((size_t)E * 4);
  float* cwn   = (float*)take((size_t)E * 4);
  float* t1    = (float*)take(NF * 4);
  float* t2    = (float*)take(NF * 4);
  float* xz    = (float*)take(NF * 4);
  float* xr    = (float*)take(NF * 4);
  float* xh    = (float*)take(NF * 4);
  float* Gb    = (float*)take(NF * 4);
  // --- bf16 tier: batched bases + gather shadows, ~186 MB more (total ~258 MB) ---
  ushort_t* Xb   = (ushort_t*)take(NF * 2 * SEQLEN);  // bf16(X), gather source
  ushort_t* t1xb = (ushort_t*)take(NF * 2 * SEQLEN);  // T1(X) bases, bf16
  ushort_t* t2xb = (ushort_t*)take(NF * 2 * SEQLEN);  // T2(X) bases, bf16
  ushort_t* Hbb  = (ushort_t*)take(NF * 2);
  ushort_t* Gbb  = (ushort_t*)take(NF * 2);
  ushort_t* t1b  = (ushort_t*)take(NF * 2);
  size_t off_bf = off;
  (void)n_in; (void)out_size;
  const bool useBF = (off_bf <= ws_size);

  hipMemsetAsync(deg, 0, (size_t)N * 4, stream);
  hipMemsetAsync(cnt, 0, (size_t)N * 4, stream);

  const int ebl = (E + 255) / 256;
  const int nbl = (N + 255) / 256;
  edge_hist_kernel<<<ebl, 256, 0, stream>>>(ei, ewt, deg, cnt, E);
  dinv_kernel<<<nbl, 256, 0, stream>>>(deg, dinv, N);
  scan_part_kernel<<<nbl, 256, 0, stream>>>(cnt, bsum, N);
  scan_top_kernel<<<1, 256, 0, stream>>>(bsum, nbl);
  scan_fill_kernel<<<nbl, 256, 0, stream>>>(cnt, bsum, rowp, woff, N, E);
  scatter_kernel<<<ebl, 256, 0, stream>>>(ei, ewt, dinv, woff, ccol, cwn, E);

  const int nq = (N + 3) / 4;
  const int g3x = (N + 63) / 64;
  const int n4 = (int)(NF / 4);
  const int ewbl = (n4 + 255) / 256;

  if (useBF) {
    // Batched X-side Chebyshev bases, bf16-only outputs (halves write traffic).
    long long xn4 = (long long)(NF * SEQLEN / 4);
    cvt_bf_kernel<<<(int)((xn4 + 255) / 256), 256, 0, stream>>>((const float4*)X, Xb, xn4);
    spmv_bf_kernel<<<dim3(nq, SEQLEN), 256, 0, stream>>>(
        rowp, ccol, cwn, Xb, X, nullptr, t1xb, 1.f, 0.f, N, (long long)NF);
    spmv_bf_kernel<<<dim3(nq, SEQLEN), 256, 0, stream>>>(
        rowp, ccol, cwn, t1xb, X, nullptr, t2xb, 2.f, -1.f, N, (long long)NF);

    for (int t = 0; t < SEQLEN; ++t) {
      const float* Xt = X + (size_t)t * NF;
      float* outt = out + (size_t)t * NF;

      // X-side gate partials for this step (A: X fp32, T1/T2 bf16)
      FG px = {};
      px.A[0] = Xt;
      px.AB[1] = t1xb + (size_t)t * NF;
      px.AB[2] = t2xb + (size_t)t * NF;
      px.W[0] = W_xz; px.W[1] = W_xr; px.W[2] = W_xh;
      px.Bv[0] = b_xz; px.Bv[1] = b_xr; px.Bv[2] = b_xh;
      px.O[0] = xz; px.O[1] = xr; px.O[2] = xh;
      px.n = N; px.tstride = 0;
      gemmf_kernel<0, 3><<<dim3(g3x, 1, 1), 256, 0, stream>>>(px);

      if (t == 0) {
        t0_kernel<<<ewbl, 256, 0, stream>>>((const float4*)xz, (const float4*)xh,
                                            b_hz, b_hh, (float4*)outt, Hbb, n4);
        continue;
      }
      const float* H = out + (size_t)(t - 1) * NF;

      // H-side basis (bf16 gather; fp32 y kept for GEMM-A precision)
      spmv_bf_kernel<<<dim3(nq, 1), 256, 0, stream>>>(rowp, ccol, cwn, Hbb, H, t1, t1b, 1.f, 0.f, N, 0);
      spmv_bf_kernel<<<dim3(nq, 1), 256, 0, stream>>>(rowp, ccol, cwn, t1b, H, t2, nullptr, 2.f, -1.f, N, 0);
      FG ph = {};
      ph.A[0] = H; ph.A[1] = t1; ph.A[2] = t2;
      ph.W[0] = W_hz; ph.W[1] = W_hr;
      ph.Bv[0] = b_hz; ph.Bv[1] = b_hr;
      ph.P[0] = xz; ph.P[1] = xr;
      ph.Hb = H;
      ph.O[0] = xz;   // Z
      ph.O[1] = Gb;   // G = H*R
      ph.OB0 = Gbb;
      ph.n = N; ph.tstride = 0;
      gemmf_kernel<1, 2><<<dim3(g3x, 1, 1), 256, 0, stream>>>(ph);

      // (H*R)-side basis + fused (h | tanh | GRU blend) -> outt (+ bf16 H shadow)
      spmv_bf_kernel<<<dim3(nq, 1), 256, 0, stream>>>(rowp, ccol, cwn, Gbb, Gb, t1, t1b, 1.f, 0.f, N, 0);
      spmv_bf_kernel<<<dim3(nq, 1), 256, 0, stream>>>(rowp, ccol, cwn, t1b, Gb, t2, nullptr, 2.f, -1.f, N, 0);
      FG pg = {};
      pg.A[0] = Gb; pg.A[1] = t1; pg.A[2] = t2;
      pg.W[0] = W_hh;
      pg.Bv[0] = b_hh;
      pg.P[0] = xh;
      pg.Zb = xz;
      pg.Hb = H;
      pg.O[0] = outt;
      pg.OB0 = (t < SEQLEN - 1) ? Hbb : nullptr;
      pg.n = N; pg.tstride = 0;
      gemmf_kernel<2, 1><<<dim3(g3x, 1, 1), 256, 0, stream>>>(pg);
    }
  } else {
    // fp32 fallback (per-step everything; fits in ~97 MB)
    for (int t = 0; t < SEQLEN; ++t) {
      const float* Xt = X + (size_t)t * NF;
      float* outt = out + (size_t)t * NF;

      spmv_kernel<<<dim3(nq, 1), 256, 0, stream>>>(rowp, ccol, cwn, Xt, Xt, t1, 1.f, 0.f, N, 0);
      spmv_kernel<<<dim3(nq, 1), 256, 0, stream>>>(rowp, ccol, cwn, t1, Xt, t2, 2.f, -1.f, N, 0);
      FG px = {};
      px.A[0] = Xt; px.A[1] = t1; px.A[2] = t2;
      px.W[0] = W_xz; px.W[1] = W_xr; px.W[2] = W_xh;
      px.Bv[0] = b_xz; px.Bv[1] = b_xr; px.Bv[2] = b_xh;
      px.O[0] = xz; px.O[1] = xr; px.O[2] = xh;
      px.n = N; px.tstride = 0;
      gemmf_kernel<0, 3><<<dim3(g3x, 1, 1), 256, 0, stream>>>(px);

      if (t == 0) {
        t0_kernel<<<ewbl, 256, 0, stream>>>((const float4*)xz, (const float4*)xh,
                                            b_hz, b_hh, (float4*)outt, nullptr, n4);
        continue;
      }
      const float* H = out + (size_t)(t - 1) * NF;

      spmv_kernel<<<dim3(nq, 1), 256, 0, stream>>>(rowp, ccol, cwn, H, H, t1, 1.f, 0.f, N, 0);
      spmv_kernel<<<dim3(nq, 1), 256, 0, stream>>>(rowp, ccol, cwn, t1, H, t2, 2.f, -1.f, N, 0);
      FG ph = {};
      ph.A[0] = H; ph.A[1] = t1; ph.A[2] = t2;
      ph.W[0] = W_hz; ph.W[1] = W_hr;
      ph.Bv[0] = b_hz; ph.Bv[1] = b_hr;
      ph.P[0] = xz; ph.P[1] = xr;
      ph.Hb = H;
      ph.O[0] = xz;
      ph.O[1] = Gb;
      ph.n = N; ph.tstride = 0;
      gemmf_kernel<1, 2><<<dim3(g3x, 1, 1), 256, 0, stream>>>(ph);

      spmv_kernel<<<dim3(nq, 1), 256, 0, stream>>>(rowp, ccol, cwn, Gb, Gb, t1, 1.f, 0.f, N, 0);
      spmv_kernel<<<dim3(nq, 1), 256, 0, stream>>>(rowp, ccol, cwn, t1, Gb, t2, 2.f, -1.f, N, 0);
      FG pg = {};
      pg.A[0] = Gb; pg.A[1] = t1; pg.A[2] = t2;
      pg.W[0] = W_hh;
      pg.Bv[0] = b_hh;
      pg.P[0] = xh;
      pg.Zb = xz;
      pg.Hb = H;
      pg.O[0] = outt;
      pg.n = N; pg.tstride = 0;
      gemmf_kernel<2, 1><<<dim3(g3x, 1, 1), 256, 0, stream>>>(pg);
    }
  }

  // Hlast = States[:, L-1]
  hipMemcpyAsync(out + (size_t)SEQLEN * NF, out + (size_t)(SEQLEN - 1) * NF,
                 NF * 4, hipMemcpyDeviceToDevice, stream);
}

// Round 2
// 2454.864 us; speedup vs baseline: 1.1176x; 1.0538x over previous
//
#include <hip/hip_runtime.h>
#include <cmath>

#define SEQLEN 8
#define CH 64  // IN_CH == HID == 64

typedef unsigned short ushort_t;

__device__ __forceinline__ ushort_t f2bf(float f) {
  union { float f; unsigned u; } v; v.f = f;
  unsigned r = v.u + 0x7fff + ((v.u >> 16) & 1);  // round-nearest-even
  return (ushort_t)(r >> 16);
}
__device__ __forceinline__ float bf2f(ushort_t h) {
  union { unsigned u; float f; } v; v.u = ((unsigned)h) << 16;
  return v.f;
}

// ---- setup: degree + count histogram over rows ----
__global__ __launch_bounds__(256) void edge_hist_kernel(
    const int* __restrict__ ei, const float* __restrict__ ew,
    float* __restrict__ deg, int* __restrict__ cnt, int E) {
  int e = blockIdx.x * 256 + threadIdx.x;
  if (e >= E) return;
  int r = ei[e];
  int c = ei[E + e];
  float wv = (r == c) ? 0.f : ew[e];
  atomicAdd(deg + r, wv);
  atomicAdd(cnt + r, 1);
}

__global__ __launch_bounds__(256) void dinv_kernel(
    const float* __restrict__ deg, float* __restrict__ dinv, int n) {
  int i = blockIdx.x * 256 + threadIdx.x;
  if (i >= n) return;
  float d = deg[i];
  dinv[i] = (d > 0.f) ? (1.0f / sqrtf(d)) : 0.f;
}

// ---- hierarchical scan ----
__global__ __launch_bounds__(256) void scan_part_kernel(
    const int* __restrict__ cnt, int* __restrict__ bsum, int n) {
  int i = blockIdx.x * 256 + threadIdx.x;
  int v = (i < n) ? cnt[i] : 0;
#pragma unroll
  for (int o = 32; o; o >>= 1) v += __shfl_down(v, o, 64);
  __shared__ int red[4];
  if ((threadIdx.x & 63) == 0) red[threadIdx.x >> 6] = v;
  __syncthreads();
  if (threadIdx.x == 0) bsum[blockIdx.x] = red[0] + red[1] + red[2] + red[3];
}

__global__ __launch_bounds__(256) void scan_top_kernel(int* __restrict__ bsum, int nb) {
  int tid = threadIdx.x, lane = tid & 63, wid = tid >> 6;
  int v = (tid < nb) ? bsum[tid] : 0;
  int orig = v;
#pragma unroll
  for (int o = 1; o < 64; o <<= 1) { int t = __shfl_up(v, o, 64); if (lane >= o) v += t; }
  __shared__ int wsum[4];
  if (lane == 63) wsum[wid] = v;
  __syncthreads();
  int base = 0;
  for (int w = 0; w < wid; ++w) base += wsum[w];
  if (tid < nb) bsum[tid] = base + v - orig;
}

__global__ __launch_bounds__(256) void scan_fill_kernel(
    const int* __restrict__ cnt, const int* __restrict__ bsum,
    int* __restrict__ rowp, int* __restrict__ woff, int n, int total) {
  int i = blockIdx.x * 256 + threadIdx.x;
  int tid = threadIdx.x, lane = tid & 63, wid = tid >> 6;
  int v = (i < n) ? cnt[i] : 0;
  int orig = v;
#pragma unroll
  for (int o = 1; o < 64; o <<= 1) { int t = __shfl_up(v, o, 64); if (lane >= o) v += t; }
  __shared__ int wsum[4];
  if (lane == 63) wsum[wid] = v;
  __syncthreads();
  int base = bsum[blockIdx.x];
  for (int w = 0; w < wid; ++w) base += wsum[w];
  if (i < n) { int ex = base + v - orig; rowp[i] = ex; woff[i] = ex; }
  if (blockIdx.x == 0 && tid == 0) rowp[n] = total;
}

__global__ __launch_bounds__(256) void scatter_kernel(
    const int* __restrict__ ei, const float* __restrict__ ew,
    const float* __restrict__ dinv, int* __restrict__ woff,
    int* __restrict__ ccol, float* __restrict__ cwn, int E) {
  int e = blockIdx.x * 256 + threadIdx.x;
  if (e >= E) return;
  int r = ei[e];
  int c = ei[E + e];
  float wv = (r == c) ? 0.f : ew[e];
  float wn = -wv * dinv[r] * dinv[c];
  int pos = atomicAdd(woff + r, 1);
  ccol[pos] = c;
  cwn[pos] = wn;
}

// fp32 [slab][node][ch] -> bf16 transposed [node][slab][ch]
__global__ __launch_bounds__(256) void cvt_bt_kernel(
    const float* __restrict__ X, ushort_t* __restrict__ Xt,
    long long NF, long long total4) {
  long long i = (long long)blockIdx.x * 256 + threadIdx.x;
  if (i >= total4) return;
  long long e4 = i * 4;                 // output element offset
  int node = (int)(e4 >> 9);            // /512
  int rem = (int)(e4 & 511);
  int slab = rem >> 6;
  int cb = rem & 63;
  const float* src = X + (size_t)slab * NF + (size_t)node * CH + cb;
  float4 v = *(const float4*)src;
  ushort4 o;
  o.x = f2bf(v.x); o.y = f2bf(v.y); o.z = f2bf(v.z); o.w = f2bf(v.w);
  *(ushort4*)(Xt + e4) = o;
}

// ---- SpMV, fp32 payload (fallback tier) ----
__global__ __launch_bounds__(256) void spmv_kernel(
    const int* __restrict__ rowp, const int* __restrict__ ccol,
    const float* __restrict__ cwn, const float* __restrict__ v,
    const float* __restrict__ u, float* __restrict__ y,
    float alpha, float beta, int n, long long slab_stride) {
  int r = blockIdx.x * 4 + (threadIdx.x >> 6);
  if (r >= n) return;
  long long so = (long long)blockIdx.y * slab_stride;
  const float* __restrict__ vs = v + so;
  const float* __restrict__ us = u + so;
  float* __restrict__ ys = y + so;
  int lane = threadIdx.x & 63;
  int s = __builtin_amdgcn_readfirstlane(rowp[r]);
  int e = __builtin_amdgcn_readfirstlane(rowp[r + 1]);
  float a0 = 0.f, a1 = 0.f, a2 = 0.f, a3 = 0.f;
  int i = s;
  for (; i + 4 <= e; i += 4) {
    int c0 = ccol[i], c1 = ccol[i + 1], c2 = ccol[i + 2], c3 = ccol[i + 3];
    float w0 = cwn[i], w1 = cwn[i + 1], w2 = cwn[i + 2], w3 = cwn[i + 3];
    float x0 = vs[(size_t)c0 * CH + lane];
    float x1 = vs[(size_t)c1 * CH + lane];
    float x2 = vs[(size_t)c2 * CH + lane];
    float x3 = vs[(size_t)c3 * CH + lane];
    a0 = fmaf(w0, x0, a0); a1 = fmaf(w1, x1, a1);
    a2 = fmaf(w2, x2, a2); a3 = fmaf(w3, x3, a3);
  }
  for (; i < e; ++i) a0 = fmaf(cwn[i], vs[(size_t)ccol[i] * CH + lane], a0);
  float res = alpha * ((a0 + a1) + (a2 + a3));
  if (beta != 0.f) res += beta * us[(size_t)r * CH + lane];
  ys[(size_t)r * CH + lane] = res;
}

// ---- Batched 8-slab SpMV over transposed bf16 layout [node][slab][ch] ----
// Per edge: ONE 1KB coalesced wave gather (16B/lane) serves all 8 slabs.
// Edge metadata chunked 16-deep, broadcast via readlane -> fully unrolled
// independent gathers (out-of-range j clamps to e-1 with w=0: L1-hit dups).
__global__ __launch_bounds__(256) void spmv_bt_kernel(
    const int* __restrict__ rowp, const int* __restrict__ ccol,
    const float* __restrict__ cwn, const ushort_t* __restrict__ v,
    const float* __restrict__ u, ushort_t* __restrict__ yt,
    float alpha, float beta, int n, long long NF) {
  int r = blockIdx.x * 4 + (threadIdx.x >> 6);
  if (r >= n) return;
  int lane = threadIdx.x & 63;
  int s = __builtin_amdgcn_readfirstlane(rowp[r]);
  int e = __builtin_amdgcn_readfirstlane(rowp[r + 1]);
  float acc[8];
#pragma unroll
  for (int k = 0; k < 8; ++k) acc[k] = 0.f;
  const ushort_t* __restrict__ vl = v + (size_t)lane * 8;  // 16B per lane
  for (int i = s; i < e; i += 16) {
    int idxl = i + (lane & 15);
    int last = e - 1;
    if (idxl > last) idxl = last;
    int cL = ccol[idxl];
    float wL = cwn[idxl];
    int jv = e - i;  // wave-uniform
#pragma unroll
    for (int j = 0; j < 16; ++j) {
      int cj = __builtin_amdgcn_readlane(cL, j);
      int wb = __builtin_amdgcn_readlane(__float_as_int(wL), j);
      float wj = (j < jv) ? __int_as_float(wb) : 0.f;
      union { float4 f4; ushort_t us[8]; } tt;
      tt.f4 = *(const float4*)(vl + (size_t)cj * (SEQLEN * CH));
#pragma unroll
      for (int k = 0; k < 8; ++k)
        acc[k] = fmaf(wj, bf2f(tt.us[k]), acc[k]);
    }
  }
  float res[8];
#pragma unroll
  for (int k = 0; k < 8; ++k) res[k] = alpha * acc[k];
  if (beta != 0.f) {
    // u: fp32 original layout [slab][node][ch]
    const float* up = u + (size_t)(lane >> 3) * NF + (size_t)r * CH + (size_t)(lane & 7) * 8;
    float4 ua = *(const float4*)up;
    float4 ub = *(const float4*)(up + 4);
    res[0] += beta * ua.x; res[1] += beta * ua.y; res[2] += beta * ua.z; res[3] += beta * ua.w;
    res[4] += beta * ub.x; res[5] += beta * ub.y; res[6] += beta * ub.z; res[7] += beta * ub.w;
  }
  union { float4 f4; ushort_t us[8]; } o;
#pragma unroll
  for (int k = 0; k < 8; ++k) o.us[k] = f2bf(res[k]);
  *(float4*)(yt + (size_t)r * (SEQLEN * CH) + (size_t)lane * 8) = o.f4;
}

// ---- Per-step SpMV, bf16 gather, chunked-16 readlane broadcast ----
__global__ __launch_bounds__(256) void spmv_bfx_kernel(
    const int* __restrict__ rowp, const int* __restrict__ ccol,
    const float* __restrict__ cwn, const ushort_t* __restrict__ v,
    const float* __restrict__ u, float* __restrict__ y, ushort_t* __restrict__ yb,
    float alpha, float beta, int n) {
  int r = blockIdx.x * 4 + (threadIdx.x >> 6);
  if (r >= n) return;
  int lane = threadIdx.x & 63;
  int s = __builtin_amdgcn_readfirstlane(rowp[r]);
  int e = __builtin_amdgcn_readfirstlane(rowp[r + 1]);
  float a0 = 0.f, a1 = 0.f, a2 = 0.f, a3 = 0.f;
  for (int i = s; i < e; i += 16) {
    int idxl = i + (lane & 15);
    int last = e - 1;
    if (idxl > last) idxl = last;
    int cL = ccol[idxl];
    float wL = cwn[idxl];
    int jv = e - i;  // wave-uniform
#pragma unroll
    for (int j = 0; j < 16; ++j) {
      int cj = __builtin_amdgcn_readlane(cL, j);
      int wb = __builtin_amdgcn_readlane(__float_as_int(wL), j);
      float wj = (j < jv) ? __int_as_float(wb) : 0.f;
      float xv = bf2f(v[(size_t)cj * CH + lane]);
      if ((j & 3) == 0) a0 = fmaf(wj, xv, a0);
      else if ((j & 3) == 1) a1 = fmaf(wj, xv, a1);
      else if ((j & 3) == 2) a2 = fmaf(wj, xv, a2);
      else a3 = fmaf(wj, xv, a3);
    }
  }
  float res = alpha * ((a0 + a1) + (a2 + a3));
  if (beta != 0.f) res += beta * u[(size_t)r * CH + lane];
  size_t oi = (size_t)r * CH + lane;
  if (y) y[oi] = res;
  if (yb) yb[oi] = f2bf(res);
}

// ---- fused multi-gate GEMM ----
struct FG {
  const float* A[3];       // fp32 A slab (used when AB[kk] == nullptr)
  const ushort_t* AB[3];   // bf16 A slab (takes precedence); node stride = abstride
  const float* W[3];
  const float* Bv[3];
  const float* P[3];
  const float* Hb;
  const float* Zb;
  float* O[3];
  ushort_t* OB0;  // optional bf16 shadow: MODE1 -> of O[1]; MODE2 -> of O[0]
  int n;
  long long tstride;
  long long abstride;      // element stride per node for AB buffers
};

__device__ __forceinline__ void fma_tile(float (&acc)[4][4], const float* At,
                                         const float* Wt, int r0, int c0) {
#pragma unroll 4
  for (int k = 0; k < 64; ++k) {
    float4 a = *(const float4*)(At + k * 68 + r0);
    float4 w = *(const float4*)(Wt + k * 64 + c0);
    float av[4] = { a.x, a.y, a.z, a.w };
    float wv[4] = { w.x, w.y, w.z, w.w };
#pragma unroll
    for (int i = 0; i < 4; ++i)
#pragma unroll
      for (int j = 0; j < 4; ++j)
        acc[i][j] = fmaf(av[i], wv[j], acc[i][j]);
  }
}

__device__ __forceinline__ float sigf(float x) { return 1.f / (1.f + expf(-x)); }

template <int MODE, int G>
__global__ __launch_bounds__(256) void gemmf_kernel(FG p) {
  __shared__ float At[64 * 68];
  __shared__ float Wt[64 * 64];
  const int tid = threadIdx.x;
  const int n0 = blockIdx.x * 64;
  const int r0 = (tid >> 4) << 2;
  const int c0 = (tid & 15) << 2;
  const long long toff = (long long)blockIdx.z * p.tstride;
  float acc[G][4][4];
#pragma unroll
  for (int g = 0; g < G; ++g)
#pragma unroll
    for (int i = 0; i < 4; ++i)
#pragma unroll
      for (int j = 0; j < 4; ++j) acc[g][i][j] = 0.f;

  for (int kk = 0; kk < 3; ++kk) {
    const float* __restrict__ A = p.A[kk] ? (p.A[kk] + toff) : nullptr;
    const ushort_t* __restrict__ Ab = p.AB[kk];
    __syncthreads();
#pragma unroll
    for (int j = 0; j < 4; ++j) {
      int flat = tid + 256 * j;
      int r = flat >> 4;
      int k4 = (flat & 15) << 2;
      int nn = n0 + r;
      float4 av;
      if (nn < p.n) {
        if (Ab) {
          ushort4 uv = *(const ushort4*)(Ab + (size_t)nn * p.abstride + k4);
          av = make_float4(bf2f(uv.x), bf2f(uv.y), bf2f(uv.z), bf2f(uv.w));
        } else {
          av = *(const float4*)(A + (size_t)nn * CH + k4);
        }
      } else {
        av = make_float4(0.f, 0.f, 0.f, 0.f);
      }
      At[(k4 + 0) * 68 + r] = av.x;
      At[(k4 + 1) * 68 + r] = av.y;
      At[(k4 + 2) * 68 + r] = av.z;
      At[(k4 + 3) * 68 + r] = av.w;
    }
#pragma unroll
    for (int g = 0; g < G; ++g) {
      if (g > 0) __syncthreads();
      const float* __restrict__ Wk = p.W[g] + kk * 4096;
#pragma unroll
      for (int j = 0; j < 4; ++j) {
        int flat = tid + 256 * j;
        *(float4*)(Wt + flat * 4) = *(const float4*)(Wk + flat * 4);
      }
      __syncthreads();
      fma_tile(acc[g], At, Wt, r0, c0);
    }
  }

  if (MODE == 0) {
#pragma unroll
    for (int g = 0; g < G; ++g) {
      float4 bv = *(const float4*)(p.Bv[g] + c0);
      float* og = p.O[g] + toff;
#pragma unroll
      for (int i = 0; i < 4; ++i) {
        int nn = n0 + r0 + i;
        if (nn < p.n) {
          float4 o;
          o.x = acc[g][i][0] + bv.x;
          o.y = acc[g][i][1] + bv.y;
          o.z = acc[g][i][2] + bv.z;
          o.w = acc[g][i][3] + bv.w;
          *(float4*)(og + (size_t)nn * CH + c0) = o;
        }
      }
    }
  } else if (MODE == 1) {
    float4 bz = *(const float4*)(p.Bv[0] + c0);
    float4 br = *(const float4*)(p.Bv[1] + c0);
#pragma unroll
    for (int i = 0; i < 4; ++i) {
      int nn = n0 + r0 + i;
      if (nn < p.n) {
        size_t idx = (size_t)nn * CH + c0;
        float4 pz = *(const float4*)(p.P[0] + idx);
        float4 pr = *(const float4*)(p.P[1] + idx);
        float4 h4 = *(const float4*)(p.Hb + idx);
        float4 z, gg;
        z.x = sigf(pz.x + bz.x + acc[0][i][0]);
        z.y = sigf(pz.y + bz.y + acc[0][i][1]);
        z.z = sigf(pz.z + bz.z + acc[0][i][2]);
        z.w = sigf(pz.w + bz.w + acc[0][i][3]);
        gg.x = h4.x * sigf(pr.x + br.x + acc[1][i][0]);
        gg.y = h4.y * sigf(pr.y + br.y + acc[1][i][1]);
        gg.z = h4.z * sigf(pr.z + br.z + acc[1][i][2]);
        gg.w = h4.w * sigf(pr.w + br.w + acc[1][i][3]);
        *(float4*)(p.O[0] + idx) = z;
        *(float4*)(p.O[1] + idx) = gg;
        if (p.OB0) {
          ushort4 ob;
          ob.x = f2bf(gg.x); ob.y = f2bf(gg.y);
          ob.z = f2bf(gg.z); ob.w = f2bf(gg.w);
          *(ushort4*)(p.OB0 + idx) = ob;
        }
      }
    }
  } else {
    float4 bh = *(const float4*)(p.Bv[0] + c0);
#pragma unroll
    for (int i = 0; i < 4; ++i) {
      int nn = n0 + r0 + i;
      if (nn < p.n) {
        size_t idx = (size_t)nn * CH + c0;
        float4 ph = *(const float4*)(p.P[0] + idx);
        float4 z4 = *(const float4*)(p.Zb + idx);
        float4 h4 = *(const float4*)(p.Hb + idx);
        float4 o;
        float t0 = tanhf(ph.x + bh.x + acc[0][i][0]);
        float t1 = tanhf(ph.y + bh.y + acc[0][i][1]);
        float t2 = tanhf(ph.z + bh.z + acc[0][i][2]);
        float t3 = tanhf(ph.w + bh.w + acc[0][i][3]);
        o.x = z4.x * h4.x + (1.f - z4.x) * t0;
        o.y = z4.y * h4.y + (1.f - z4.y) * t1;
        o.z = z4.z * h4.z + (1.f - z4.z) * t2;
        o.w = z4.w * h4.w + (1.f - z4.w) * t3;
        *(float4*)(p.O[0] + idx) = o;
        if (p.OB0) {
          ushort4 ob;
          ob.x = f2bf(o.x); ob.y = f2bf(o.y);
          ob.z = f2bf(o.z); ob.w = f2bf(o.w);
          *(ushort4*)(p.OB0 + idx) = ob;
        }
      }
    }
  }
}

// t=0: H=0 => out0 = (1-sig(xzp+b_hz)) * tanh(xhp+b_hh); also bf16 shadow for step 1
__global__ __launch_bounds__(256) void t0_kernel(
    const float4* __restrict__ xzp, const float4* __restrict__ xhp,
    const float* __restrict__ b_hz, const float* __restrict__ b_hh,
    float4* __restrict__ out0, ushort_t* __restrict__ out0b, int n4) {
  int i = blockIdx.x * 256 + threadIdx.x;
  if (i >= n4) return;
  int cb = (i << 2) & 63;
  float4 bz = *(const float4*)(b_hz + cb);
  float4 bh = *(const float4*)(b_hh + cb);
  float4 z4 = xzp[i], h4 = xhp[i];
  float4 o;
  o.x = (1.f - sigf(z4.x + bz.x)) * tanhf(h4.x + bh.x);
  o.y = (1.f - sigf(z4.y + bz.y)) * tanhf(h4.y + bh.y);
  o.z = (1.f - sigf(z4.z + bz.z)) * tanhf(h4.z + bh.z);
  o.w = (1.f - sigf(z4.w + bz.w)) * tanhf(h4.w + bh.w);
  out0[i] = o;
  if (out0b) {
    ushort4 ob;
    ob.x = f2bf(o.x); ob.y = f2bf(o.y); ob.z = f2bf(o.z); ob.w = f2bf(o.w);
    *(ushort4*)(out0b + (size_t)i * 4) = ob;
  }
}

extern "C" void kernel_launch(void* const* d_in, const int* in_sizes, int n_in,
                              void* d_out, int out_size, void* d_ws, size_t ws_size,
                              hipStream_t stream) {
  const float* X    = (const float*)d_in[0];
  const int*   ei   = (const int*)d_in[1];
  const float* ewt  = (const float*)d_in[2];
  const float* W_xz = (const float*)d_in[3];  const float* b_xz = (const float*)d_in[4];
  const float* W_hz = (const float*)d_in[5];  const float* b_hz = (const float*)d_in[6];
  const float* W_xr = (const float*)d_in[7];  const float* b_xr = (const float*)d_in[8];
  const float* W_hr = (const float*)d_in[9];  const float* b_hr = (const float*)d_in[10];
  const float* W_xh = (const float*)d_in[11]; const float* b_xh = (const float*)d_in[12];
  const float* W_hh = (const float*)d_in[13]; const float* b_hh = (const float*)d_in[14];

  const int N = in_sizes[0] / (SEQLEN * CH);
  const int E = in_sizes[1] / 2;
  const size_t NF = (size_t)N * CH;
  float* out = (float*)d_out;

  char* base = (char*)d_ws;
  size_t off = 0;
  auto take = [&](size_t bytes) -> void* {
    off = (off + 255) & ~(size_t)255;
    void* p = base + off;
    off += bytes;
    return p;
  };
  // --- fp32 core (needed by all tiers) ---
  float* deg   = (float*)take((size_t)N * 4);
  float* dinv  = (float*)take((size_t)N * 4);
  int*   cnt   = (int*)take((size_t)N * 4);
  int*   rowp  = (int*)take((size_t)(N + 1) * 4);
  int*   woff  = (int*)take((size_t)(N + 1) * 4);
  int*   bsum  = (int*)take(1024 * 4);
  int*   ccol  = (int*)take((size_t)E * 4);
  float* cwn   = (float*)take((size_t)E * 4);
  float* t1    = (float*)take(NF * 4);
  float* t2    = (float*)take(NF * 4);
  float* xz    = (float*)take(NF * 4);
  float* xr    = (float*)take(NF * 4);
  float* xh    = (float*)take(NF * 4);
  float* Gb    = (float*)take(NF * 4);
  // --- bf16 tier: transposed [node][slab][ch] bases + gather shadows ---
  ushort_t* Xb   = (ushort_t*)take(NF * 2 * SEQLEN);  // bf16(X), transposed
  ushort_t* t1xb = (ushort_t*)take(NF * 2 * SEQLEN);  // T1(X), transposed
  ushort_t* t2xb = (ushort_t*)take(NF * 2 * SEQLEN);  // T2(X), transposed
  ushort_t* Hbb  = (ushort_t*)take(NF * 2);
  ushort_t* Gbb  = (ushort_t*)take(NF * 2);
  ushort_t* t1b  = (ushort_t*)take(NF * 2);
  size_t off_bf = off;
  (void)n_in; (void)out_size;
  const bool useBF = (off_bf <= ws_size);

  hipMemsetAsync(deg, 0, (size_t)N * 4, stream);
  hipMemsetAsync(cnt, 0, (size_t)N * 4, stream);

  const int ebl = (E + 255) / 256;
  const int nbl = (N + 255) / 256;
  edge_hist_kernel<<<ebl, 256, 0, stream>>>(ei, ewt, deg, cnt, E);
  dinv_kernel<<<nbl, 256, 0, stream>>>(deg, dinv, N);
  scan_part_kernel<<<nbl, 256, 0, stream>>>(cnt, bsum, N);
  scan_top_kernel<<<1, 256, 0, stream>>>(bsum, nbl);
  scan_fill_kernel<<<nbl, 256, 0, stream>>>(cnt, bsum, rowp, woff, N, E);
  scatter_kernel<<<ebl, 256, 0, stream>>>(ei, ewt, dinv, woff, ccol, cwn, E);

  const int nq = (N + 3) / 4;
  const int g3x = (N + 63) / 64;
  const int n4 = (int)(NF / 4);
  const int ewbl = (n4 + 255) / 256;

  if (useBF) {
    // Batched X-side Chebyshev bases over transposed layout.
    long long xn4 = (long long)(NF * SEQLEN / 4);
    cvt_bt_kernel<<<(int)((xn4 + 255) / 256), 256, 0, stream>>>(X, Xb, (long long)NF, xn4);
    spmv_bt_kernel<<<dim3(nq, 1), 256, 0, stream>>>(
        rowp, ccol, cwn, Xb, nullptr, t1xb, 1.f, 0.f, N, (long long)NF);
    spmv_bt_kernel<<<dim3(nq, 1), 256, 0, stream>>>(
        rowp, ccol, cwn, t1xb, X, t2xb, 2.f, -1.f, N, (long long)NF);

    for (int t = 0; t < SEQLEN; ++t) {
      const float* Xt = X + (size_t)t * NF;
      float* outt = out + (size_t)t * NF;

      // X-side gate partials for this step (A: X fp32; T1/T2 bf16 transposed)
      FG px = {};
      px.A[0] = Xt;
      px.AB[1] = t1xb + (size_t)t * CH;
      px.AB[2] = t2xb + (size_t)t * CH;
      px.abstride = SEQLEN * CH;
      px.W[0] = W_xz; px.W[1] = W_xr; px.W[2] = W_xh;
      px.Bv[0] = b_xz; px.Bv[1] = b_xr; px.Bv[2] = b_xh;
      px.O[0] = xz; px.O[1] = xr; px.O[2] = xh;
      px.n = N; px.tstride = 0;
      gemmf_kernel<0, 3><<<dim3(g3x, 1, 1), 256, 0, stream>>>(px);

      if (t == 0) {
        t0_kernel<<<ewbl, 256, 0, stream>>>((const float4*)xz, (const float4*)xh,
                                            b_hz, b_hh, (float4*)outt, Hbb, n4);
        continue;
      }
      const float* H = out + (size_t)(t - 1) * NF;

      // H-side basis (bf16 gather; fp32 y kept for GEMM-A precision)
      spmv_bfx_kernel<<<dim3(nq, 1), 256, 0, stream>>>(rowp, ccol, cwn, Hbb, H, t1, t1b, 1.f, 0.f, N);
      spmv_bfx_kernel<<<dim3(nq, 1), 256, 0, stream>>>(rowp, ccol, cwn, t1b, H, t2, nullptr, 2.f, -1.f, N);
      FG ph = {};
      ph.A[0] = H; ph.A[1] = t1; ph.A[2] = t2;
      ph.W[0] = W_hz; ph.W[1] = W_hr;
      ph.Bv[0] = b_hz; ph.Bv[1] = b_hr;
      ph.P[0] = xz; ph.P[1] = xr;
      ph.Hb = H;
      ph.O[0] = xz;   // Z
      ph.O[1] = Gb;   // G = H*R
      ph.OB0 = Gbb;
      ph.n = N; ph.tstride = 0;
      gemmf_kernel<1, 2><<<dim3(g3x, 1, 1), 256, 0, stream>>>(ph);

      // (H*R)-side basis + fused (h | tanh | GRU blend) -> outt (+ bf16 H shadow)
      spmv_bfx_kernel<<<dim3(nq, 1), 256, 0, stream>>>(rowp, ccol, cwn, Gbb, Gb, t1, t1b, 1.f, 0.f, N);
      spmv_bfx_kernel<<<dim3(nq, 1), 256, 0, stream>>>(rowp, ccol, cwn, t1b, Gb, t2, nullptr, 2.f, -1.f, N);
      FG pg = {};
      pg.A[0] = Gb; pg.A[1] = t1; pg.A[2] = t2;
      pg.W[0] = W_hh;
      pg.Bv[0] = b_hh;
      pg.P[0] = xh;
      pg.Zb = xz;
      pg.Hb = H;
      pg.O[0] = outt;
      pg.OB0 = (t < SEQLEN - 1) ? Hbb : nullptr;
      pg.n = N; pg.tstride = 0;
      gemmf_kernel<2, 1><<<dim3(g3x, 1, 1), 256, 0, stream>>>(pg);
    }
  } else {
    // fp32 fallback (per-step everything)
    for (int t = 0; t < SEQLEN; ++t) {
      const float* Xt = X + (size_t)t * NF;
      float* outt = out + (size_t)t * NF;

      spmv_kernel<<<dim3(nq, 1), 256, 0, stream>>>(rowp, ccol, cwn, Xt, Xt, t1, 1.f, 0.f, N, 0);
      spmv_kernel<<<dim3(nq, 1), 256, 0, stream>>>(rowp, ccol, cwn, t1, Xt, t2, 2.f, -1.f, N, 0);
      FG px = {};
      px.A[0] = Xt; px.A[1] = t1; px.A[2] = t2;
      px.W[0] = W_xz; px.W[1] = W_xr; px.W[2] = W_xh;
      px.Bv[0] = b_xz; px.Bv[1] = b_xr; px.Bv[2] = b_xh;
      px.O[0] = xz; px.O[1] = xr; px.O[2] = xh;
      px.n = N; px.tstride = 0;
      gemmf_kernel<0, 3><<<dim3(g3x, 1, 1), 256, 0, stream>>>(px);

      if (t == 0) {
        t0_kernel<<<ewbl, 256, 0, stream>>>((const float4*)xz, (const float4*)xh,
                                            b_hz, b_hh, (float4*)outt, nullptr, n4);
        continue;
      }
      const float* H = out + (size_t)(t - 1) * NF;

      spmv_kernel<<<dim3(nq, 1), 256, 0, stream>>>(rowp, ccol, cwn, H, H, t1, 1.f, 0.f, N, 0);
      spmv_kernel<<<dim3(nq, 1), 256, 0, stream>>>(rowp, ccol, cwn, t1, H, t2, 2.f, -1.f, N, 0);
      FG ph = {};
      ph.A[0] = H; ph.A[1] = t1; ph.A[2] = t2;
      ph.W[0] = W_hz; ph.W[1] = W_hr;
      ph.Bv[0] = b_hz; ph.Bv[1] = b_hr;
      ph.P[0] = xz; ph.P[1] = xr;
      ph.Hb = H;
      ph.O[0] = xz;
      ph.O[1] = Gb;
      ph.n = N; ph.tstride = 0;
      gemmf_kernel<1, 2><<<dim3(g3x, 1, 1), 256, 0, stream>>>(ph);

      spmv_kernel<<<dim3(nq, 1), 256, 0, stream>>>(rowp, ccol, cwn, Gb, Gb, t1, 1.f, 0.f, N, 0);
      spmv_kernel<<<dim3(nq, 1), 256, 0, stream>>>(rowp, ccol, cwn, t1, Gb, t2, 2.f, -1.f, N, 0);
      FG pg = {};
      pg.A[0] = Gb; pg.A[1] = t1; pg.A[2] = t2;
      pg.W[0] = W_hh;
      pg.Bv[0] = b_hh;
      pg.P[0] = xh;
      pg.Zb = xz;
      pg.Hb = H;
      pg.O[0] = outt;
      pg.n = N; pg.tstride = 0;
      gemmf_kernel<2, 1><<<dim3(g3x, 1, 1), 256, 0, stream>>>(pg);
    }
  }

  // Hlast = States[:, L-1]
  hipMemcpyAsync(out + (size_t)SEQLEN * NF, out + (size_t)(SEQLEN - 1) * NF,
                 NF * 4, hipMemcpyDeviceToDevice, stream);
}

// Round 5
// 2071.250 us; speedup vs baseline: 1.3246x; 1.1852x over previous
//
#include <hip/hip_runtime.h>
#include <cmath>

#define SEQLEN 8
#define CH 64  // IN_CH == HID == 64

typedef unsigned short ushort_t;
typedef __attribute__((ext_vector_type(8))) short bf16x8;
typedef __attribute__((ext_vector_type(4))) float f32x4;

__device__ __forceinline__ ushort_t f2bf(float f) {
  union { float f; unsigned u; } v; v.f = f;
  unsigned r = v.u + 0x7fff + ((v.u >> 16) & 1);  // round-nearest-even
  return (ushort_t)(r >> 16);
}
__device__ __forceinline__ float bf2f(ushort_t h) {
  union { unsigned u; float f; } v; v.u = ((unsigned)h) << 16;
  return v.f;
}

// ---- setup: degree + count histogram over rows ----
__global__ __launch_bounds__(256) void edge_hist_kernel(
    const int* __restrict__ ei, const float* __restrict__ ew,
    float* __restrict__ deg, int* __restrict__ cnt, int E) {
  int e = blockIdx.x * 256 + threadIdx.x;
  if (e >= E) return;
  int r = ei[e];
  int c = ei[E + e];
  float wv = (r == c) ? 0.f : ew[e];
  atomicAdd(deg + r, wv);
  atomicAdd(cnt + r, 1);
}

__global__ __launch_bounds__(256) void dinv_kernel(
    const float* __restrict__ deg, float* __restrict__ dinv, int n) {
  int i = blockIdx.x * 256 + threadIdx.x;
  if (i >= n) return;
  float d = deg[i];
  dinv[i] = (d > 0.f) ? (1.0f / sqrtf(d)) : 0.f;
}

// ---- hierarchical scan ----
__global__ __launch_bounds__(256) void scan_part_kernel(
    const int* __restrict__ cnt, int* __restrict__ bsum, int n) {
  int i = blockIdx.x * 256 + threadIdx.x;
  int v = (i < n) ? cnt[i] : 0;
#pragma unroll
  for (int o = 32; o; o >>= 1) v += __shfl_down(v, o, 64);
  __shared__ int red[4];
  if ((threadIdx.x & 63) == 0) red[threadIdx.x >> 6] = v;
  __syncthreads();
  if (threadIdx.x == 0) bsum[blockIdx.x] = red[0] + red[1] + red[2] + red[3];
}

__global__ __launch_bounds__(256) void scan_top_kernel(int* __restrict__ bsum, int nb) {
  int tid = threadIdx.x, lane = tid & 63, wid = tid >> 6;
  int v = (tid < nb) ? bsum[tid] : 0;
  int orig = v;
#pragma unroll
  for (int o = 1; o < 64; o <<= 1) { int t = __shfl_up(v, o, 64); if (lane >= o) v += t; }
  __shared__ int wsum[4];
  if (lane == 63) wsum[wid] = v;
  __syncthreads();
  int base = 0;
  for (int w = 0; w < wid; ++w) base += wsum[w];
  if (tid < nb) bsum[tid] = base + v - orig;
}

__global__ __launch_bounds__(256) void scan_fill_kernel(
    const int* __restrict__ cnt, const int* __restrict__ bsum,
    int* __restrict__ rowp, int* __restrict__ woff, int n, int total) {
  int i = blockIdx.x * 256 + threadIdx.x;
  int tid = threadIdx.x, lane = tid & 63, wid = tid >> 6;
  int v = (i < n) ? cnt[i] : 0;
  int orig = v;
#pragma unroll
  for (int o = 1; o < 64; o <<= 1) { int t = __shfl_up(v, o, 64); if (lane >= o) v += t; }
  __shared__ int wsum[4];
  if (lane == 63) wsum[wid] = v;
  __syncthreads();
  int base = bsum[blockIdx.x];
  for (int w = 0; w < wid; ++w) base += wsum[w];
  if (i < n) { int ex = base + v - orig; rowp[i] = ex; woff[i] = ex; }
  if (blockIdx.x == 0 && tid == 0) rowp[n] = total;
}

__global__ __launch_bounds__(256) void scatter_kernel(
    const int* __restrict__ ei, const float* __restrict__ ew,
    const float* __restrict__ dinv, int* __restrict__ woff,
    int* __restrict__ ccol, float* __restrict__ cwn, int E) {
  int e = blockIdx.x * 256 + threadIdx.x;
  if (e >= E) return;
  int r = ei[e];
  int c = ei[E + e];
  float wv = (r == c) ? 0.f : ew[e];
  float wn = -wv * dinv[r] * dinv[c];
  int pos = atomicAdd(woff + r, 1);
  ccol[pos] = c;
  cwn[pos] = wn;
}

// fp32 [slab][node][ch] -> bf16 transposed [node][slab][ch]
__global__ __launch_bounds__(256) void cvt_bt_kernel(
    const float* __restrict__ X, ushort_t* __restrict__ Xt,
    long long NF, long long total4) {
  long long i = (long long)blockIdx.x * 256 + threadIdx.x;
  if (i >= total4) return;
  long long e4 = i * 4;                 // output element offset
  int node = (int)(e4 >> 9);            // /512
  int rem = (int)(e4 & 511);
  int slab = rem >> 6;
  int cb = rem & 63;
  const float* src = X + (size_t)slab * NF + (size_t)node * CH + cb;
  float4 v = *(const float4*)src;
  ushort4 o;
  o.x = f2bf(v.x); o.y = f2bf(v.y); o.z = f2bf(v.z); o.w = f2bf(v.w);
  *(ushort4*)(Xt + e4) = o;
}

// weights fp32 [3][k=64][c=64] -> bf16 transposed [3][c=64][k=64]
__global__ __launch_bounds__(256) void cvt_wt_kernel(
    const float* __restrict__ W, ushort_t* __restrict__ Wt) {
  int i = blockIdx.x * 256 + threadIdx.x;
  if (i >= 3 * 4096) return;
  int kk = i >> 12, rem = i & 4095, c = rem >> 6, k = rem & 63;
  Wt[i] = f2bf(W[(kk << 12) + (k << 6) + c]);
}

// ---- SpMV, fp32 payload (fallback tier) ----
__global__ __launch_bounds__(256) void spmv_kernel(
    const int* __restrict__ rowp, const int* __restrict__ ccol,
    const float* __restrict__ cwn, const float* __restrict__ v,
    const float* __restrict__ u, float* __restrict__ y,
    float alpha, float beta, int n, long long slab_stride) {
  int r = blockIdx.x * 4 + (threadIdx.x >> 6);
  if (r >= n) return;
  long long so = (long long)blockIdx.y * slab_stride;
  const float* __restrict__ vs = v + so;
  const float* __restrict__ us = u + so;
  float* __restrict__ ys = y + so;
  int lane = threadIdx.x & 63;
  int s = __builtin_amdgcn_readfirstlane(rowp[r]);
  int e = __builtin_amdgcn_readfirstlane(rowp[r + 1]);
  float a0 = 0.f, a1 = 0.f, a2 = 0.f, a3 = 0.f;
  int i = s;
  for (; i + 4 <= e; i += 4) {
    int c0 = ccol[i], c1 = ccol[i + 1], c2 = ccol[i + 2], c3 = ccol[i + 3];
    float w0 = cwn[i], w1 = cwn[i + 1], w2 = cwn[i + 2], w3 = cwn[i + 3];
    float x0 = vs[(size_t)c0 * CH + lane];
    float x1 = vs[(size_t)c1 * CH + lane];
    float x2 = vs[(size_t)c2 * CH + lane];
    float x3 = vs[(size_t)c3 * CH + lane];
    a0 = fmaf(w0, x0, a0); a1 = fmaf(w1, x1, a1);
    a2 = fmaf(w2, x2, a2); a3 = fmaf(w3, x3, a3);
  }
  for (; i < e; ++i) a0 = fmaf(cwn[i], vs[(size_t)ccol[i] * CH + lane], a0);
  float res = alpha * ((a0 + a1) + (a2 + a3));
  if (beta != 0.f) res += beta * us[(size_t)r * CH + lane];
  ys[(size_t)r * CH + lane] = res;
}

// ---- Batched 8-slab SpMV over transposed bf16 layout [node][slab][ch] ----
__global__ __launch_bounds__(256) void spmv_bt_kernel(
    const int* __restrict__ rowp, const int* __restrict__ ccol,
    const float* __restrict__ cwn, const ushort_t* __restrict__ v,
    const float* __restrict__ u, ushort_t* __restrict__ yt,
    float alpha, float beta, int n, long long NF) {
  int r = blockIdx.x * 4 + (threadIdx.x >> 6);
  if (r >= n) return;
  int lane = threadIdx.x & 63;
  int s = __builtin_amdgcn_readfirstlane(rowp[r]);
  int e = __builtin_amdgcn_readfirstlane(rowp[r + 1]);
  float acc[8];
#pragma unroll
  for (int k = 0; k < 8; ++k) acc[k] = 0.f;
  const ushort_t* __restrict__ vl = v + (size_t)lane * 8;  // 16B per lane
  for (int i = s; i < e; i += 16) {
    int idxl = i + (lane & 15);
    int last = e - 1;
    if (idxl > last) idxl = last;
    int cL = ccol[idxl];
    float wL = cwn[idxl];
    int jv = e - i;  // wave-uniform
#pragma unroll
    for (int j = 0; j < 16; ++j) {
      int cj = __builtin_amdgcn_readlane(cL, j);
      int wb = __builtin_amdgcn_readlane(__float_as_int(wL), j);
      float wj = (j < jv) ? __int_as_float(wb) : 0.f;
      union { float4 f4; ushort_t us[8]; } tt;
      tt.f4 = *(const float4*)(vl + (size_t)cj * (SEQLEN * CH));
#pragma unroll
      for (int k = 0; k < 8; ++k)
        acc[k] = fmaf(wj, bf2f(tt.us[k]), acc[k]);
    }
  }
  float res[8];
#pragma unroll
  for (int k = 0; k < 8; ++k) res[k] = alpha * acc[k];
  if (beta != 0.f) {
    // u: fp32 original layout [slab][node][ch]
    const float* up = u + (size_t)(lane >> 3) * NF + (size_t)r * CH + (size_t)(lane & 7) * 8;
    float4 ua = *(const float4*)up;
    float4 ub = *(const float4*)(up + 4);
    res[0] += beta * ua.x; res[1] += beta * ua.y; res[2] += beta * ua.z; res[3] += beta * ua.w;
    res[4] += beta * ub.x; res[5] += beta * ub.y; res[6] += beta * ub.z; res[7] += beta * ub.w;
  }
  union { float4 f4; ushort_t us[8]; } o;
#pragma unroll
  for (int k = 0; k < 8; ++k) o.us[k] = f2bf(res[k]);
  *(float4*)(yt + (size_t)r * (SEQLEN * CH) + (size_t)lane * 8) = o.f4;
}

// ---- Per-step SpMV, bf16 gather, chunked-16 readlane broadcast ----
__global__ __launch_bounds__(256) void spmv_bfx_kernel(
    const int* __restrict__ rowp, const int* __restrict__ ccol,
    const float* __restrict__ cwn, const ushort_t* __restrict__ v,
    const float* __restrict__ u, float* __restrict__ y, ushort_t* __restrict__ yb,
    float alpha, float beta, int n) {
  int r = blockIdx.x * 4 + (threadIdx.x >> 6);
  if (r >= n) return;
  int lane = threadIdx.x & 63;
  int s = __builtin_amdgcn_readfirstlane(rowp[r]);
  int e = __builtin_amdgcn_readfirstlane(rowp[r + 1]);
  float a0 = 0.f, a1 = 0.f, a2 = 0.f, a3 = 0.f;
  for (int i = s; i < e; i += 16) {
    int idxl = i + (lane & 15);
    int last = e - 1;
    if (idxl > last) idxl = last;
    int cL = ccol[idxl];
    float wL = cwn[idxl];
    int jv = e - i;  // wave-uniform
#pragma unroll
    for (int j = 0; j < 16; ++j) {
      int cj = __builtin_amdgcn_readlane(cL, j);
      int wb = __builtin_amdgcn_readlane(__float_as_int(wL), j);
      float wj = (j < jv) ? __int_as_float(wb) : 0.f;
      float xv = bf2f(v[(size_t)cj * CH + lane]);
      if ((j & 3) == 0) a0 = fmaf(wj, xv, a0);
      else if ((j & 3) == 1) a1 = fmaf(wj, xv, a1);
      else if ((j & 3) == 2) a2 = fmaf(wj, xv, a2);
      else a3 = fmaf(wj, xv, a3);
    }
  }
  float res = alpha * ((a0 + a1) + (a2 + a3));
  if (beta != 0.f) res += beta * u[(size_t)r * CH + lane];
  size_t oi = (size_t)r * CH + lane;
  if (y) y[oi] = res;
  if (yb) yb[oi] = f2bf(res);
}

__device__ __forceinline__ float sigf(float x) { return 1.f / (1.f + expf(-x)); }

// ---- MFMA fused multi-gate GEMM (bf16 A, bf16 W^T, fp32 acc) ----
// Block: 4 waves x 32 rows = 128 nodes, 64 cols. Per wave: 2 row-tiles x 4 col-tiles.
// A frag: lane reads A[row=lane&15][k = 8*(lane>>4) + s*32 .. +7] (16B contiguous).
// B frag: W pre-transposed [c][k]; lane reads Wt[c=lane&15][same k] (16B contiguous).
// C/D: col = lane&15, row = (lane>>4)*4 + reg  [guide m89, HW-verified].
struct FGM {
  const ushort_t* AB[3];   // bf16 A slabs, node stride = abstride
  const ushort_t* WB[3];   // bf16 W^T, [kk][c][k], 3*4096 elems each
  const float* Bv[3];
  const float* P[2];
  const float* Hb;
  const float* Zb;
  float* O[3];
  ushort_t* OB0;           // optional bf16 shadow: MODE1 -> O[1]; MODE2 -> O[0]
  int n;
  long long abstride;
};

template <int MODE, int G>
__global__ __launch_bounds__(256) void gemm_mfma_kernel(FGM p) {
  const int tid = threadIdx.x;
  const int wave = tid >> 6, lane = tid & 63;
  const int lr = lane & 15, kg = lane >> 4;
  const int wrow = blockIdx.x * 128 + wave * 32;
  f32x4 acc[G][2][4];
#pragma unroll
  for (int g = 0; g < G; ++g)
#pragma unroll
    for (int m = 0; m < 2; ++m)
#pragma unroll
      for (int ct = 0; ct < 4; ++ct) acc[g][m][ct] = (f32x4)0.f;

#pragma unroll
  for (int kk = 0; kk < 3; ++kk) {
    const ushort_t* __restrict__ Ab = p.AB[kk];
    bf16x8 a[2][2];
#pragma unroll
    for (int m = 0; m < 2; ++m) {
      int nn = wrow + m * 16 + lr;
      if (nn >= p.n) nn = p.n - 1;
      const ushort_t* ap = Ab + (size_t)nn * p.abstride + kg * 8;
      a[m][0] = *(const bf16x8*)(ap);
      a[m][1] = *(const bf16x8*)(ap + 32);
    }
#pragma unroll
    for (int g = 0; g < G; ++g) {
      const ushort_t* __restrict__ Wg = p.WB[g] + kk * 4096 + lr * 64 + kg * 8;
#pragma unroll
      for (int ct = 0; ct < 4; ++ct) {
        bf16x8 b0 = *(const bf16x8*)(Wg + ct * 1024);
        bf16x8 b1 = *(const bf16x8*)(Wg + ct * 1024 + 32);
        acc[g][0][ct] = __builtin_amdgcn_mfma_f32_16x16x32_bf16(a[0][0], b0, acc[g][0][ct], 0, 0, 0);
        acc[g][0][ct] = __builtin_amdgcn_mfma_f32_16x16x32_bf16(a[0][1], b1, acc[g][0][ct], 0, 0, 0);
        acc[g][1][ct] = __builtin_amdgcn_mfma_f32_16x16x32_bf16(a[1][0], b0, acc[g][1][ct], 0, 0, 0);
        acc[g][1][ct] = __builtin_amdgcn_mfma_f32_16x16x32_bf16(a[1][1], b1, acc[g][1][ct], 0, 0, 0);
      }
    }
  }

  if (MODE == 0) {
#pragma unroll
    for (int g = 0; g < G; ++g) {
#pragma unroll
      for (int ct = 0; ct < 4; ++ct) {
        int col = ct * 16 + lr;
        float bv = p.Bv[g][col];
#pragma unroll
        for (int m = 0; m < 2; ++m) {
#pragma unroll
          for (int i = 0; i < 4; ++i) {
            int row = wrow + m * 16 + kg * 4 + i;
            if (row < p.n) p.O[g][(size_t)row * CH + col] = acc[g][m][ct][i] + bv;
          }
        }
      }
    }
  } else if (MODE == 1) {
#pragma unroll
    for (int ct = 0; ct < 4; ++ct) {
      int col = ct * 16 + lr;
      float bz = p.Bv[0][col];
      float br = p.Bv[1][col];
#pragma unroll
      for (int m = 0; m < 2; ++m) {
#pragma unroll
        for (int i = 0; i < 4; ++i) {
          int row = wrow + m * 16 + kg * 4 + i;
          if (row < p.n) {
            size_t idx = (size_t)row * CH + col;
            float z = sigf(p.P[0][idx] + bz + acc[0][m][ct][i]);
            float gg = p.Hb[idx] * sigf(p.P[1][idx] + br + acc[1][m][ct][i]);
            p.O[0][idx] = z;
            p.O[1][idx] = gg;
            if (p.OB0) p.OB0[idx] = f2bf(gg);
          }
        }
      }
    }
  } else {
#pragma unroll
    for (int ct = 0; ct < 4; ++ct) {
      int col = ct * 16 + lr;
      float bh = p.Bv[0][col];
#pragma unroll
      for (int m = 0; m < 2; ++m) {
#pragma unroll
        for (int i = 0; i < 4; ++i) {
          int row = wrow + m * 16 + kg * 4 + i;
          if (row < p.n) {
            size_t idx = (size_t)row * CH + col;
            float tv = tanhf(p.P[0][idx] + bh + acc[0][m][ct][i]);
            float z4 = p.Zb[idx];
            float o = z4 * p.Hb[idx] + (1.f - z4) * tv;
            p.O[0][idx] = o;
            if (p.OB0) p.OB0[idx] = f2bf(o);
          }
        }
      }
    }
  }
}

// ---- VALU fused GEMM (fp32 fallback tier) ----
struct FG {
  const float* A[3];
  const float* W[3];
  const float* Bv[3];
  const float* P[3];
  const float* Hb;
  const float* Zb;
  float* O[3];
  int n;
};

__device__ __forceinline__ void fma_tile(float (&acc)[4][4], const float* At,
                                         const float* Wt, int r0, int c0) {
#pragma unroll 4
  for (int k = 0; k < 64; ++k) {
    float4 a = *(const float4*)(At + k * 68 + r0);
    float4 w = *(const float4*)(Wt + k * 64 + c0);
    float av[4] = { a.x, a.y, a.z, a.w };
    float wv[4] = { w.x, w.y, w.z, w.w };
#pragma unroll
    for (int i = 0; i < 4; ++i)
#pragma unroll
      for (int j = 0; j < 4; ++j)
        acc[i][j] = fmaf(av[i], wv[j], acc[i][j]);
  }
}

template <int MODE, int G>
__global__ __launch_bounds__(256) void gemmf_kernel(FG p) {
  __shared__ float At[64 * 68];
  __shared__ float Wt[64 * 64];
  const int tid = threadIdx.x;
  const int n0 = blockIdx.x * 64;
  const int r0 = (tid >> 4) << 2;
  const int c0 = (tid & 15) << 2;
  float acc[G][4][4];
#pragma unroll
  for (int g = 0; g < G; ++g)
#pragma unroll
    for (int i = 0; i < 4; ++i)
#pragma unroll
      for (int j = 0; j < 4; ++j) acc[g][i][j] = 0.f;

  for (int kk = 0; kk < 3; ++kk) {
    const float* __restrict__ A = p.A[kk];
    __syncthreads();
#pragma unroll
    for (int j = 0; j < 4; ++j) {
      int flat = tid + 256 * j;
      int r = flat >> 4;
      int k4 = (flat & 15) << 2;
      int nn = n0 + r;
      float4 av = (nn < p.n) ? *(const float4*)(A + (size_t)nn * CH + k4)
                             : make_float4(0.f, 0.f, 0.f, 0.f);
      At[(k4 + 0) * 68 + r] = av.x;
      At[(k4 + 1) * 68 + r] = av.y;
      At[(k4 + 2) * 68 + r] = av.z;
      At[(k4 + 3) * 68 + r] = av.w;
    }
#pragma unroll
    for (int g = 0; g < G; ++g) {
      if (g > 0) __syncthreads();
      const float* __restrict__ Wk = p.W[g] + kk * 4096;
#pragma unroll
      for (int j = 0; j < 4; ++j) {
        int flat = tid + 256 * j;
        *(float4*)(Wt + flat * 4) = *(const float4*)(Wk + flat * 4);
      }
      __syncthreads();
      fma_tile(acc[g], At, Wt, r0, c0);
    }
  }

  if (MODE == 0) {
#pragma unroll
    for (int g = 0; g < G; ++g) {
      float4 bv = *(const float4*)(p.Bv[g] + c0);
#pragma unroll
      for (int i = 0; i < 4; ++i) {
        int nn = n0 + r0 + i;
        if (nn < p.n) {
          float4 o;
          o.x = acc[g][i][0] + bv.x;
          o.y = acc[g][i][1] + bv.y;
          o.z = acc[g][i][2] + bv.z;
          o.w = acc[g][i][3] + bv.w;
          *(float4*)(p.O[g] + (size_t)nn * CH + c0) = o;
        }
      }
    }
  } else if (MODE == 1) {
    float4 bz = *(const float4*)(p.Bv[0] + c0);
    float4 br = *(const float4*)(p.Bv[1] + c0);
#pragma unroll
    for (int i = 0; i < 4; ++i) {
      int nn = n0 + r0 + i;
      if (nn < p.n) {
        size_t idx = (size_t)nn * CH + c0;
        float4 pz = *(const float4*)(p.P[0] + idx);
        float4 pr = *(const float4*)(p.P[1] + idx);
        float4 h4 = *(const float4*)(p.Hb + idx);
        float4 z, gg;
        z.x = sigf(pz.x + bz.x + acc[0][i][0]);
        z.y = sigf(pz.y + bz.y + acc[0][i][1]);
        z.z = sigf(pz.z + bz.z + acc[0][i][2]);
        z.w = sigf(pz.w + bz.w + acc[0][i][3]);
        gg.x = h4.x * sigf(pr.x + br.x + acc[1][i][0]);
        gg.y = h4.y * sigf(pr.y + br.y + acc[1][i][1]);
        gg.z = h4.z * sigf(pr.z + br.z + acc[1][i][2]);
        gg.w = h4.w * sigf(pr.w + br.w + acc[1][i][3]);
        *(float4*)(p.O[0] + idx) = z;
        *(float4*)(p.O[1] + idx) = gg;
      }
    }
  } else {
    float4 bh = *(const float4*)(p.Bv[0] + c0);
#pragma unroll
    for (int i = 0; i < 4; ++i) {
      int nn = n0 + r0 + i;
      if (nn < p.n) {
        size_t idx = (size_t)nn * CH + c0;
        float4 ph = *(const float4*)(p.P[0] + idx);
        float4 z4 = *(const float4*)(p.Zb + idx);
        float4 h4 = *(const float4*)(p.Hb + idx);
        float4 o;
        float t0 = tanhf(ph.x + bh.x + acc[0][i][0]);
        float t1 = tanhf(ph.y + bh.y + acc[0][i][1]);
        float t2 = tanhf(ph.z + bh.z + acc[0][i][2]);
        float t3 = tanhf(ph.w + bh.w + acc[0][i][3]);
        o.x = z4.x * h4.x + (1.f - z4.x) * t0;
        o.y = z4.y * h4.y + (1.f - z4.y) * t1;
        o.z = z4.z * h4.z + (1.f - z4.z) * t2;
        o.w = z4.w * h4.w + (1.f - z4.w) * t3;
        *(float4*)(p.O[0] + idx) = o;
      }
    }
  }
}

// t=0: H=0 => out0 = (1-sig(xzp+b_hz)) * tanh(xhp+b_hh); also bf16 shadow for step 1
__global__ __launch_bounds__(256) void t0_kernel(
    const float4* __restrict__ xzp, const float4* __restrict__ xhp,
    const float* __restrict__ b_hz, const float* __restrict__ b_hh,
    float4* __restrict__ out0, ushort_t* __restrict__ out0b, int n4) {
  int i = blockIdx.x * 256 + threadIdx.x;
  if (i >= n4) return;
  int cb = (i << 2) & 63;
  float4 bz = *(const float4*)(b_hz + cb);
  float4 bh = *(const float4*)(b_hh + cb);
  float4 z4 = xzp[i], h4 = xhp[i];
  float4 o;
  o.x = (1.f - sigf(z4.x + bz.x)) * tanhf(h4.x + bh.x);
  o.y = (1.f - sigf(z4.y + bz.y)) * tanhf(h4.y + bh.y);
  o.z = (1.f - sigf(z4.z + bz.z)) * tanhf(h4.z + bh.z);
  o.w = (1.f - sigf(z4.w + bz.w)) * tanhf(h4.w + bh.w);
  out0[i] = o;
  if (out0b) {
    ushort4 ob;
    ob.x = f2bf(o.x); ob.y = f2bf(o.y); ob.z = f2bf(o.z); ob.w = f2bf(o.w);
    *(ushort4*)(out0b + (size_t)i * 4) = ob;
  }
}

extern "C" void kernel_launch(void* const* d_in, const int* in_sizes, int n_in,
                              void* d_out, int out_size, void* d_ws, size_t ws_size,
                              hipStream_t stream) {
  const float* X    = (const float*)d_in[0];
  const int*   ei   = (const int*)d_in[1];
  const float* ewt  = (const float*)d_in[2];
  const float* W_xz = (const float*)d_in[3];  const float* b_xz = (const float*)d_in[4];
  const float* W_hz = (const float*)d_in[5];  const float* b_hz = (const float*)d_in[6];
  const float* W_xr = (const float*)d_in[7];  const float* b_xr = (const float*)d_in[8];
  const float* W_hr = (const float*)d_in[9];  const float* b_hr = (const float*)d_in[10];
  const float* W_xh = (const float*)d_in[11]; const float* b_xh = (const float*)d_in[12];
  const float* W_hh = (const float*)d_in[13]; const float* b_hh = (const float*)d_in[14];

  const int N = in_sizes[0] / (SEQLEN * CH);
  const int E = in_sizes[1] / 2;
  const size_t NF = (size_t)N * CH;
  float* out = (float*)d_out;

  char* base = (char*)d_ws;
  size_t off = 0;
  auto take = [&](size_t bytes) -> void* {
    off = (off + 255) & ~(size_t)255;
    void* p = base + off;
    off += bytes;
    return p;
  };
  // --- fp32 core (needed by all tiers) ---
  float* deg   = (float*)take((size_t)N * 4);
  float* dinv  = (float*)take((size_t)N * 4);
  int*   cnt   = (int*)take((size_t)N * 4);
  int*   rowp  = (int*)take((size_t)(N + 1) * 4);
  int*   woff  = (int*)take((size_t)(N + 1) * 4);
  int*   bsum  = (int*)take(1024 * 4);
  int*   ccol  = (int*)take((size_t)E * 4);
  float* cwn   = (float*)take((size_t)E * 4);
  float* t1    = (float*)take(NF * 4);
  float* t2    = (float*)take(NF * 4);
  float* xz    = (float*)take(NF * 4);
  float* xr    = (float*)take(NF * 4);
  float* xh    = (float*)take(NF * 4);
  float* Gb    = (float*)take(NF * 4);
  // --- bf16 tier: transposed [node][slab][ch] bases + gather shadows + bf16 W^T ---
  ushort_t* Xb   = (ushort_t*)take(NF * 2 * SEQLEN);  // bf16(X), transposed
  ushort_t* t1xb = (ushort_t*)take(NF * 2 * SEQLEN);  // T1(X), transposed
  ushort_t* t2xb = (ushort_t*)take(NF * 2 * SEQLEN);  // T2(X), transposed
  ushort_t* Hbb  = (ushort_t*)take(NF * 2);
  ushort_t* Gbb  = (ushort_t*)take(NF * 2);
  ushort_t* t1b  = (ushort_t*)take(NF * 2);
  ushort_t* t2b  = (ushort_t*)take(NF * 2);
  ushort_t* Wxzb = (ushort_t*)take(3 * 4096 * 2);
  ushort_t* Wxrb = (ushort_t*)take(3 * 4096 * 2);
  ushort_t* Wxhb = (ushort_t*)take(3 * 4096 * 2);
  ushort_t* Whzb = (ushort_t*)take(3 * 4096 * 2);
  ushort_t* Whrb = (ushort_t*)take(3 * 4096 * 2);
  ushort_t* Whhb = (ushort_t*)take(3 * 4096 * 2);
  size_t off_bf = off;
  (void)n_in; (void)out_size;
  const bool useBF = (off_bf <= ws_size);

  hipMemsetAsync(deg, 0, (size_t)N * 4, stream);
  hipMemsetAsync(cnt, 0, (size_t)N * 4, stream);

  const int ebl = (E + 255) / 256;
  const int nbl = (N + 255) / 256;
  edge_hist_kernel<<<ebl, 256, 0, stream>>>(ei, ewt, deg, cnt, E);
  dinv_kernel<<<nbl, 256, 0, stream>>>(deg, dinv, N);
  scan_part_kernel<<<nbl, 256, 0, stream>>>(cnt, bsum, N);
  scan_top_kernel<<<1, 256, 0, stream>>>(bsum, nbl);
  scan_fill_kernel<<<nbl, 256, 0, stream>>>(cnt, bsum, rowp, woff, N, E);
  scatter_kernel<<<ebl, 256, 0, stream>>>(ei, ewt, dinv, woff, ccol, cwn, E);

  const int nq = (N + 3) / 4;
  const int g3x = (N + 63) / 64;
  const int gmx = (N + 127) / 128;
  const int n4 = (int)(NF / 4);
  const int ewbl = (n4 + 255) / 256;

  if (useBF) {
    // bf16 W^T conversions (tiny)
    cvt_wt_kernel<<<48, 256, 0, stream>>>(W_xz, Wxzb);
    cvt_wt_kernel<<<48, 256, 0, stream>>>(W_xr, Wxrb);
    cvt_wt_kernel<<<48, 256, 0, stream>>>(W_xh, Wxhb);
    cvt_wt_kernel<<<48, 256, 0, stream>>>(W_hz, Whzb);
    cvt_wt_kernel<<<48, 256, 0, stream>>>(W_hr, Whrb);
    cvt_wt_kernel<<<48, 256, 0, stream>>>(W_hh, Whhb);

    // Batched X-side Chebyshev bases over transposed layout.
    long long xn4 = (long long)(NF * SEQLEN / 4);
    cvt_bt_kernel<<<(int)((xn4 + 255) / 256), 256, 0, stream>>>(X, Xb, (long long)NF, xn4);
    spmv_bt_kernel<<<dim3(nq, 1), 256, 0, stream>>>(
        rowp, ccol, cwn, Xb, nullptr, t1xb, 1.f, 0.f, N, (long long)NF);
    spmv_bt_kernel<<<dim3(nq, 1), 256, 0, stream>>>(
        rowp, ccol, cwn, t1xb, X, t2xb, 2.f, -1.f, N, (long long)NF);

    for (int t = 0; t < SEQLEN; ++t) {
      float* outt = out + (size_t)t * NF;

      // X-side gate partials for this step (MFMA; A = bf16 transposed slabs)
      FGM px = {};
      px.AB[0] = Xb + (size_t)t * CH;
      px.AB[1] = t1xb + (size_t)t * CH;
      px.AB[2] = t2xb + (size_t)t * CH;
      px.WB[0] = Wxzb; px.WB[1] = Wxrb; px.WB[2] = Wxhb;
      px.Bv[0] = b_xz; px.Bv[1] = b_xr; px.Bv[2] = b_xh;
      px.O[0] = xz; px.O[1] = xr; px.O[2] = xh;
      px.n = N; px.abstride = SEQLEN * CH;
      gemm_mfma_kernel<0, 3><<<dim3(gmx, 1, 1), 256, 0, stream>>>(px);

      if (t == 0) {
        t0_kernel<<<ewbl, 256, 0, stream>>>((const float4*)xz, (const float4*)xh,
                                            b_hz, b_hh, (float4*)outt, Hbb, n4);
        continue;
      }
      const float* H = out + (size_t)(t - 1) * NF;

      // H-side basis (bf16 gather; bf16 shadows feed MFMA A)
      spmv_bfx_kernel<<<dim3(nq, 1), 256, 0, stream>>>(rowp, ccol, cwn, Hbb, H, t1, t1b, 1.f, 0.f, N);
      spmv_bfx_kernel<<<dim3(nq, 1), 256, 0, stream>>>(rowp, ccol, cwn, t1b, H, t2, t2b, 2.f, -1.f, N);
      FGM ph = {};
      ph.AB[0] = Hbb; ph.AB[1] = t1b; ph.AB[2] = t2b;
      ph.WB[0] = Whzb; ph.WB[1] = Whrb;
      ph.Bv[0] = b_hz; ph.Bv[1] = b_hr;
      ph.P[0] = xz; ph.P[1] = xr;
      ph.Hb = H;
      ph.O[0] = xz;   // Z
      ph.O[1] = Gb;   // G = H*R
      ph.OB0 = Gbb;
      ph.n = N; ph.abstride = CH;
      gemm_mfma_kernel<1, 2><<<dim3(gmx, 1, 1), 256, 0, stream>>>(ph);

      // (H*R)-side basis + fused (h | tanh | GRU blend) -> outt (+ bf16 H shadow)
      spmv_bfx_kernel<<<dim3(nq, 1), 256, 0, stream>>>(rowp, ccol, cwn, Gbb, Gb, t1, t1b, 1.f, 0.f, N);
      spmv_bfx_kernel<<<dim3(nq, 1), 256, 0, stream>>>(rowp, ccol, cwn, t1b, Gb, t2, t2b, 2.f, -1.f, N);
      FGM pg = {};
      pg.AB[0] = Gbb; pg.AB[1] = t1b; pg.AB[2] = t2b;
      pg.WB[0] = Whhb;
      pg.Bv[0] = b_hh;
      pg.P[0] = xh;
      pg.Zb = xz;
      pg.Hb = H;
      pg.O[0] = outt;
      pg.OB0 = (t < SEQLEN - 1) ? Hbb : nullptr;
      pg.n = N; pg.abstride = CH;
      gemm_mfma_kernel<2, 1><<<dim3(gmx, 1, 1), 256, 0, stream>>>(pg);
    }
  } else {
    // fp32 fallback (per-step everything, VALU GEMM)
    for (int t = 0; t < SEQLEN; ++t) {
      const float* Xt = X + (size_t)t * NF;
      float* outt = out + (size_t)t * NF;

      spmv_kernel<<<dim3(nq, 1), 256, 0, stream>>>(rowp, ccol, cwn, Xt, Xt, t1, 1.f, 0.f, N, 0);
      spmv_kernel<<<dim3(nq, 1), 256, 0, stream>>>(rowp, ccol, cwn, t1, Xt, t2, 2.f, -1.f, N, 0);
      FG px = {};
      px.A[0] = Xt; px.A[1] = t1; px.A[2] = t2;
      px.W[0] = W_xz; px.W[1] = W_xr; px.W[2] = W_xh;
      px.Bv[0] = b_xz; px.Bv[1] = b_xr; px.Bv[2] = b_xh;
      px.O[0] = xz; px.O[1] = xr; px.O[2] = xh;
      px.n = N;
      gemmf_kernel<0, 3><<<dim3(g3x, 1, 1), 256, 0, stream>>>(px);

      if (t == 0) {
        t0_kernel<<<ewbl, 256, 0, stream>>>((const float4*)xz, (const float4*)xh,
                                            b_hz, b_hh, (float4*)outt, nullptr, n4);
        continue;
      }
      const float* H = out + (size_t)(t - 1) * NF;

      spmv_kernel<<<dim3(nq, 1), 256, 0, stream>>>(rowp, ccol, cwn, H, H, t1, 1.f, 0.f, N, 0);
      spmv_kernel<<<dim3(nq, 1), 256, 0, stream>>>(rowp, ccol, cwn, t1, H, t2, 2.f, -1.f, N, 0);
      FG ph = {};
      ph.A[0] = H; ph.A[1] = t1; ph.A[2] = t2;
      ph.W[0] = W_hz; ph.W[1] = W_hr;
      ph.Bv[0] = b_hz; ph.Bv[1] = b_hr;
      ph.P[0] = xz; ph.P[1] = xr;
      ph.Hb = H;
      ph.O[0] = xz;
      ph.O[1] = Gb;
      ph.n = N;
      gemmf_kernel<1, 2><<<dim3(g3x, 1, 1), 256, 0, stream>>>(ph);

      spmv_kernel<<<dim3(nq, 1), 256, 0, stream>>>(rowp, ccol, cwn, Gb, Gb, t1, 1.f, 0.f, N, 0);
      spmv_kernel<<<dim3(nq, 1), 256, 0, stream>>>(rowp, ccol, cwn, t1, Gb, t2, 2.f, -1.f, N, 0);
      FG pg = {};
      pg.A[0] = Gb; pg.A[1] = t1; pg.A[2] = t2;
      pg.W[0] = W_hh;
      pg.Bv[0] = b_hh;
      pg.P[0] = xh;
      pg.Zb = xz;
      pg.Hb = H;
      pg.O[0] = outt;
      pg.n = N;
      gemmf_kernel<2, 1><<<dim3(g3x, 1, 1), 256, 0, stream>>>(pg);
    }
  }

  // Hlast = States[:, L-1]
  hipMemcpyAsync(out + (size_t)SEQLEN * NF, out + (size_t)(SEQLEN - 1) * NF,
                 NF * 4, hipMemcpyDeviceToDevice, stream);
}

// Round 7
// 1828.412 us; speedup vs baseline: 1.5006x; 1.1328x over previous
//
#include <hip/hip_runtime.h>
#include <cmath>

#define SEQLEN 8
#define CH 64  // IN_CH == HID == 64

typedef unsigned short ushort_t;
typedef __attribute__((ext_vector_type(8))) short bf16x8;
typedef __attribute__((ext_vector_type(4))) float f32x4;

__device__ __forceinline__ ushort_t f2bf(float f) {
  union { float f; unsigned u; } v; v.f = f;
  unsigned r = v.u + 0x7fff + ((v.u >> 16) & 1);  // round-nearest-even
  return (ushort_t)(r >> 16);
}
__device__ __forceinline__ float bf2f(ushort_t h) {
  union { unsigned u; float f; } v; v.u = ((unsigned)h) << 16;
  return v.f;
}

// ---- setup: degree + count histogram over rows ----
__global__ __launch_bounds__(256) void edge_hist_kernel(
    const int* __restrict__ ei, const float* __restrict__ ew,
    float* __restrict__ deg, int* __restrict__ cnt, int E) {
  int e = blockIdx.x * 256 + threadIdx.x;
  if (e >= E) return;
  int r = ei[e];
  int c = ei[E + e];
  float wv = (r == c) ? 0.f : ew[e];
  atomicAdd(deg + r, wv);
  atomicAdd(cnt + r, 1);
}

__global__ __launch_bounds__(256) void dinv_kernel(
    const float* __restrict__ deg, float* __restrict__ dinv, int n) {
  int i = blockIdx.x * 256 + threadIdx.x;
  if (i >= n) return;
  float d = deg[i];
  dinv[i] = (d > 0.f) ? (1.0f / sqrtf(d)) : 0.f;
}

// ---- hierarchical scan ----
__global__ __launch_bounds__(256) void scan_part_kernel(
    const int* __restrict__ cnt, int* __restrict__ bsum, int n) {
  int i = blockIdx.x * 256 + threadIdx.x;
  int v = (i < n) ? cnt[i] : 0;
#pragma unroll
  for (int o = 32; o; o >>= 1) v += __shfl_down(v, o, 64);
  __shared__ int red[4];
  if ((threadIdx.x & 63) == 0) red[threadIdx.x >> 6] = v;
  __syncthreads();
  if (threadIdx.x == 0) bsum[blockIdx.x] = red[0] + red[1] + red[2] + red[3];
}

__global__ __launch_bounds__(256) void scan_top_kernel(int* __restrict__ bsum, int nb) {
  int tid = threadIdx.x, lane = tid & 63, wid = tid >> 6;
  int v = (tid < nb) ? bsum[tid] : 0;
  int orig = v;
#pragma unroll
  for (int o = 1; o < 64; o <<= 1) { int t = __shfl_up(v, o, 64); if (lane >= o) v += t; }
  __shared__ int wsum[4];
  if (lane == 63) wsum[wid] = v;
  __syncthreads();
  int base = 0;
  for (int w = 0; w < wid; ++w) base += wsum[w];
  if (tid < nb) bsum[tid] = base + v - orig;
}

__global__ __launch_bounds__(256) void scan_fill_kernel(
    const int* __restrict__ cnt, const int* __restrict__ bsum,
    int* __restrict__ rowp, int* __restrict__ woff, int n, int total) {
  int i = blockIdx.x * 256 + threadIdx.x;
  int tid = threadIdx.x, lane = tid & 63, wid = tid >> 6;
  int v = (i < n) ? cnt[i] : 0;
  int orig = v;
#pragma unroll
  for (int o = 1; o < 64; o <<= 1) { int t = __shfl_up(v, o, 64); if (lane >= o) v += t; }
  __shared__ int wsum[4];
  if (lane == 63) wsum[wid] = v;
  __syncthreads();
  int base = bsum[blockIdx.x];
  for (int w = 0; w < wid; ++w) base += wsum[w];
  if (i < n) { int ex = base + v - orig; rowp[i] = ex; woff[i] = ex; }
  if (blockIdx.x == 0 && tid == 0) rowp[n] = total;
}

__global__ __launch_bounds__(256) void scatter_kernel(
    const int* __restrict__ ei, const float* __restrict__ ew,
    const float* __restrict__ dinv, int* __restrict__ woff,
    int* __restrict__ ccol, float* __restrict__ cwn, int E) {
  int e = blockIdx.x * 256 + threadIdx.x;
  if (e >= E) return;
  int r = ei[e];
  int c = ei[E + e];
  float wv = (r == c) ? 0.f : ew[e];
  float wn = -wv * dinv[r] * dinv[c];
  int pos = atomicAdd(woff + r, 1);
  ccol[pos] = c;
  cwn[pos] = wn;
}

// fp32 [slab][node][ch] -> bf16 transposed [node][slab][ch]
__global__ __launch_bounds__(256) void cvt_bt_kernel(
    const float* __restrict__ X, ushort_t* __restrict__ Xt,
    long long NF, long long total4) {
  long long i = (long long)blockIdx.x * 256 + threadIdx.x;
  if (i >= total4) return;
  long long e4 = i * 4;                 // output element offset
  int node = (int)(e4 >> 9);            // /512
  int rem = (int)(e4 & 511);
  int slab = rem >> 6;
  int cb = rem & 63;
  const float* src = X + (size_t)slab * NF + (size_t)node * CH + cb;
  float4 v = *(const float4*)src;
  ushort4 o;
  o.x = f2bf(v.x); o.y = f2bf(v.y); o.z = f2bf(v.z); o.w = f2bf(v.w);
  *(ushort4*)(Xt + e4) = o;
}

// weights fp32 [3][k=64][c=64] -> bf16 transposed [3][c=64][k=64]
__global__ __launch_bounds__(256) void cvt_wt_kernel(
    const float* __restrict__ W, ushort_t* __restrict__ Wt) {
  int i = blockIdx.x * 256 + threadIdx.x;
  if (i >= 3 * 4096) return;
  int kk = i >> 12, rem = i & 4095, c = rem >> 6, k = rem & 63;
  Wt[i] = f2bf(W[(kk << 12) + (k << 6) + c]);
}

// ---- SpMV, fp32 payload (fallback tier) ----
__global__ __launch_bounds__(256) void spmv_kernel(
    const int* __restrict__ rowp, const int* __restrict__ ccol,
    const float* __restrict__ cwn, const float* __restrict__ v,
    const float* __restrict__ u, float* __restrict__ y,
    float alpha, float beta, int n, long long slab_stride) {
  int r = blockIdx.x * 4 + (threadIdx.x >> 6);
  if (r >= n) return;
  long long so = (long long)blockIdx.y * slab_stride;
  const float* __restrict__ vs = v + so;
  const float* __restrict__ us = u + so;
  float* __restrict__ ys = y + so;
  int lane = threadIdx.x & 63;
  int s = __builtin_amdgcn_readfirstlane(rowp[r]);
  int e = __builtin_amdgcn_readfirstlane(rowp[r + 1]);
  float a0 = 0.f, a1 = 0.f, a2 = 0.f, a3 = 0.f;
  int i = s;
  for (; i + 4 <= e; i += 4) {
    int c0 = ccol[i], c1 = ccol[i + 1], c2 = ccol[i + 2], c3 = ccol[i + 3];
    float w0 = cwn[i], w1 = cwn[i + 1], w2 = cwn[i + 2], w3 = cwn[i + 3];
    float x0 = vs[(size_t)c0 * CH + lane];
    float x1 = vs[(size_t)c1 * CH + lane];
    float x2 = vs[(size_t)c2 * CH + lane];
    float x3 = vs[(size_t)c3 * CH + lane];
    a0 = fmaf(w0, x0, a0); a1 = fmaf(w1, x1, a1);
    a2 = fmaf(w2, x2, a2); a3 = fmaf(w3, x3, a3);
  }
  for (; i < e; ++i) a0 = fmaf(cwn[i], vs[(size_t)ccol[i] * CH + lane], a0);
  float res = alpha * ((a0 + a1) + (a2 + a3));
  if (beta != 0.f) res += beta * us[(size_t)r * CH + lane];
  ys[(size_t)r * CH + lane] = res;
}

// ---- Batched 8-slab SpMV over transposed bf16 layout [node][slab][ch] ----
__global__ __launch_bounds__(256) void spmv_bt_kernel(
    const int* __restrict__ rowp, const int* __restrict__ ccol,
    const float* __restrict__ cwn, const ushort_t* __restrict__ v,
    const float* __restrict__ u, ushort_t* __restrict__ yt,
    float alpha, float beta, int n, long long NF) {
  int r = blockIdx.x * 4 + (threadIdx.x >> 6);
  if (r >= n) return;
  int lane = threadIdx.x & 63;
  int s = __builtin_amdgcn_readfirstlane(rowp[r]);
  int e = __builtin_amdgcn_readfirstlane(rowp[r + 1]);
  float acc[8];
#pragma unroll
  for (int k = 0; k < 8; ++k) acc[k] = 0.f;
  const ushort_t* __restrict__ vl = v + (size_t)lane * 8;  // 16B per lane
  for (int i = s; i < e; i += 16) {
    int idxl = i + (lane & 15);
    int last = e - 1;
    if (idxl > last) idxl = last;
    int cL = ccol[idxl];
    float wL = cwn[idxl];
    int jv = e - i;  // wave-uniform
#pragma unroll
    for (int j = 0; j < 16; ++j) {
      int cj = __builtin_amdgcn_readlane(cL, j);
      int wb = __builtin_amdgcn_readlane(__float_as_int(wL), j);
      float wj = (j < jv) ? __int_as_float(wb) : 0.f;
      union { float4 f4; ushort_t us[8]; } tt;
      tt.f4 = *(const float4*)(vl + (size_t)cj * (SEQLEN * CH));
#pragma unroll
      for (int k = 0; k < 8; ++k)
        acc[k] = fmaf(wj, bf2f(tt.us[k]), acc[k]);
    }
  }
  float res[8];
#pragma unroll
  for (int k = 0; k < 8; ++k) res[k] = alpha * acc[k];
  if (beta != 0.f) {
    // u: fp32 original layout [slab][node][ch]
    const float* up = u + (size_t)(lane >> 3) * NF + (size_t)r * CH + (size_t)(lane & 7) * 8;
    float4 ua = *(const float4*)up;
    float4 ub = *(const float4*)(up + 4);
    res[0] += beta * ua.x; res[1] += beta * ua.y; res[2] += beta * ua.z; res[3] += beta * ua.w;
    res[4] += beta * ub.x; res[5] += beta * ub.y; res[6] += beta * ub.z; res[7] += beta * ub.w;
  }
  union { float4 f4; ushort_t us[8]; } o;
#pragma unroll
  for (int k = 0; k < 8; ++k) o.us[k] = f2bf(res[k]);
  *(float4*)(yt + (size_t)r * (SEQLEN * CH) + (size_t)lane * 8) = o.f4;
}

// ---- Per-step SpMV, bf16 gather, chunked-16 readlane broadcast ----
__global__ __launch_bounds__(256) void spmv_bfx_kernel(
    const int* __restrict__ rowp, const int* __restrict__ ccol,
    const float* __restrict__ cwn, const ushort_t* __restrict__ v,
    const float* __restrict__ u, float* __restrict__ y, ushort_t* __restrict__ yb,
    float alpha, float beta, int n) {
  int r = blockIdx.x * 4 + (threadIdx.x >> 6);
  if (r >= n) return;
  int lane = threadIdx.x & 63;
  int s = __builtin_amdgcn_readfirstlane(rowp[r]);
  int e = __builtin_amdgcn_readfirstlane(rowp[r + 1]);
  float a0 = 0.f, a1 = 0.f, a2 = 0.f, a3 = 0.f;
  for (int i = s; i < e; i += 16) {
    int idxl = i + (lane & 15);
    int last = e - 1;
    if (idxl > last) idxl = last;
    int cL = ccol[idxl];
    float wL = cwn[idxl];
    int jv = e - i;  // wave-uniform
#pragma unroll
    for (int j = 0; j < 16; ++j) {
      int cj = __builtin_amdgcn_readlane(cL, j);
      int wb = __builtin_amdgcn_readlane(__float_as_int(wL), j);
      float wj = (j < jv) ? __int_as_float(wb) : 0.f;
      float xv = bf2f(v[(size_t)cj * CH + lane]);
      if ((j & 3) == 0) a0 = fmaf(wj, xv, a0);
      else if ((j & 3) == 1) a1 = fmaf(wj, xv, a1);
      else if ((j & 3) == 2) a2 = fmaf(wj, xv, a2);
      else a3 = fmaf(wj, xv, a3);
    }
  }
  float res = alpha * ((a0 + a1) + (a2 + a3));
  if (beta != 0.f) res += beta * u[(size_t)r * CH + lane];
  size_t oi = (size_t)r * CH + lane;
  if (y) y[oi] = res;
  if (yb) yb[oi] = f2bf(res);
}

__device__ __forceinline__ float sigf(float x) { return 1.f / (1.f + expf(-x)); }

// ---- Fused X+H MFMA gate kernel ----
// MODE 0 (t=0): gates (z,h), X side only; out0 = (1-sig(z+bxz+bhz))*tanh(h+bxh+bhh)
// MODE 1: gates (z,r), X+H sides; Z=sig(.), G=H*sig(.); writes Z (fp32), G (fp32+bf16)
// MODE 2: gate (h), X+G sides; out = Z*H + (1-Z)*tanh(.)
// Block: 4 waves x 32 rows = 128 nodes. A frags 16B/lane; W^T [c][k] 16B/lane.
// C/D: col = lane&15, row = (lane>>4)*4 + reg  [guide m89, HW-verified].
struct FGF {
  const ushort_t* ABx[3];  // X-side bf16 slabs, node stride = SEQLEN*CH
  const ushort_t* ABh[3];  // H/G-side bf16 slabs, node stride = CH (unused MODE0)
  const ushort_t* WX[2];   // bf16 W^T, X side, per gate
  const ushort_t* WH[2];   // bf16 W^T, H side, per gate (unused MODE0 matmul)
  const float* BX[2];
  const float* BH[2];
  const float* Hb;         // fp32 H (MODE1/2)
  const float* Zb;         // fp32 Z (MODE2)
  float* O0;
  float* O1;               // MODE1: G fp32
  ushort_t* OB;            // bf16 shadow (MODE0/2: H; MODE1: G)
  int n;
};

template <int MODE>
__global__ __launch_bounds__(256) void gemm_fused_kernel(FGF p) {
  constexpr int G = (MODE == 2) ? 1 : 2;
  const int tid = threadIdx.x;
  const int wave = tid >> 6, lane = tid & 63;
  const int lr = lane & 15, kg = lane >> 4;
  const int wrow = blockIdx.x * 128 + wave * 32;
  f32x4 acc[G][2][4];
#pragma unroll
  for (int g = 0; g < G; ++g)
#pragma unroll
    for (int m = 0; m < 2; ++m)
#pragma unroll
      for (int ct = 0; ct < 4; ++ct) acc[g][m][ct] = (f32x4)0.f;

  int nn0 = wrow + lr;       if (nn0 >= p.n) nn0 = p.n - 1;
  int nn1 = wrow + 16 + lr;  if (nn1 >= p.n) nn1 = p.n - 1;

  // X side (stride SEQLEN*CH)
#pragma unroll
  for (int kk = 0; kk < 3; ++kk) {
    bf16x8 a[2][2];
    const ushort_t* a0p = p.ABx[kk] + (size_t)nn0 * (SEQLEN * CH) + kg * 8;
    const ushort_t* a1p = p.ABx[kk] + (size_t)nn1 * (SEQLEN * CH) + kg * 8;
    a[0][0] = *(const bf16x8*)(a0p); a[0][1] = *(const bf16x8*)(a0p + 32);
    a[1][0] = *(const bf16x8*)(a1p); a[1][1] = *(const bf16x8*)(a1p + 32);
#pragma unroll
    for (int g = 0; g < G; ++g) {
      const ushort_t* __restrict__ Wg = p.WX[g] + kk * 4096 + lr * 64 + kg * 8;
#pragma unroll
      for (int ct = 0; ct < 4; ++ct) {
        bf16x8 b0 = *(const bf16x8*)(Wg + ct * 1024);
        bf16x8 b1 = *(const bf16x8*)(Wg + ct * 1024 + 32);
        acc[g][0][ct] = __builtin_amdgcn_mfma_f32_16x16x32_bf16(a[0][0], b0, acc[g][0][ct], 0, 0, 0);
        acc[g][0][ct] = __builtin_amdgcn_mfma_f32_16x16x32_bf16(a[0][1], b1, acc[g][0][ct], 0, 0, 0);
        acc[g][1][ct] = __builtin_amdgcn_mfma_f32_16x16x32_bf16(a[1][0], b0, acc[g][1][ct], 0, 0, 0);
        acc[g][1][ct] = __builtin_amdgcn_mfma_f32_16x16x32_bf16(a[1][1], b1, acc[g][1][ct], 0, 0, 0);
      }
    }
  }

  // H/G side (stride CH)
  if (MODE != 0) {
#pragma unroll
    for (int kk = 0; kk < 3; ++kk) {
      bf16x8 a[2][2];
      const ushort_t* a0p = p.ABh[kk] + (size_t)nn0 * CH + kg * 8;
      const ushort_t* a1p = p.ABh[kk] + (size_t)nn1 * CH + kg * 8;
      a[0][0] = *(const bf16x8*)(a0p); a[0][1] = *(const bf16x8*)(a0p + 32);
      a[1][0] = *(const bf16x8*)(a1p); a[1][1] = *(const bf16x8*)(a1p + 32);
#pragma unroll
      for (int g = 0; g < G; ++g) {
        const ushort_t* __restrict__ Wg = p.WH[g] + kk * 4096 + lr * 64 + kg * 8;
#pragma unroll
        for (int ct = 0; ct < 4; ++ct) {
          bf16x8 b0 = *(const bf16x8*)(Wg + ct * 1024);
          bf16x8 b1 = *(const bf16x8*)(Wg + ct * 1024 + 32);
          acc[g][0][ct] = __builtin_amdgcn_mfma_f32_16x16x32_bf16(a[0][0], b0, acc[g][0][ct], 0, 0, 0);
          acc[g][0][ct] = __builtin_amdgcn_mfma_f32_16x16x32_bf16(a[0][1], b1, acc[g][0][ct], 0, 0, 0);
          acc[g][1][ct] = __builtin_amdgcn_mfma_f32_16x16x32_bf16(a[1][0], b0, acc[g][1][ct], 0, 0, 0);
          acc[g][1][ct] = __builtin_amdgcn_mfma_f32_16x16x32_bf16(a[1][1], b1, acc[g][1][ct], 0, 0, 0);
        }
      }
    }
  }

#pragma unroll
  for (int ct = 0; ct < 4; ++ct) {
    int col = ct * 16 + lr;
    if (MODE == 0) {
      float bz = p.BX[0][col] + p.BH[0][col];
      float bh = p.BX[1][col] + p.BH[1][col];
#pragma unroll
      for (int m = 0; m < 2; ++m)
#pragma unroll
        for (int i = 0; i < 4; ++i) {
          int row = wrow + m * 16 + kg * 4 + i;
          if (row < p.n) {
            size_t idx = (size_t)row * CH + col;
            float o = (1.f - sigf(acc[0][m][ct][i] + bz)) * tanhf(acc[1][m][ct][i] + bh);
            p.O0[idx] = o;
            p.OB[idx] = f2bf(o);
          }
        }
    } else if (MODE == 1) {
      float bz = p.BX[0][col] + p.BH[0][col];
      float br = p.BX[1][col] + p.BH[1][col];
#pragma unroll
      for (int m = 0; m < 2; ++m)
#pragma unroll
        for (int i = 0; i < 4; ++i) {
          int row = wrow + m * 16 + kg * 4 + i;
          if (row < p.n) {
            size_t idx = (size_t)row * CH + col;
            float z = sigf(acc[0][m][ct][i] + bz);
            float gg = p.Hb[idx] * sigf(acc[1][m][ct][i] + br);
            p.O0[idx] = z;
            p.O1[idx] = gg;
            p.OB[idx] = f2bf(gg);
          }
        }
    } else {
      float bh = p.BX[0][col] + p.BH[0][col];
#pragma unroll
      for (int m = 0; m < 2; ++m)
#pragma unroll
        for (int i = 0; i < 4; ++i) {
          int row = wrow + m * 16 + kg * 4 + i;
          if (row < p.n) {
            size_t idx = (size_t)row * CH + col;
            float tv = tanhf(acc[0][m][ct][i] + bh);
            float z = p.Zb[idx];
            float o = z * p.Hb[idx] + (1.f - z) * tv;
            p.O0[idx] = o;
            if (p.OB) p.OB[idx] = f2bf(o);
          }
        }
    }
  }
}

// ---- VALU fused GEMM (fp32 fallback tier) ----
struct FG {
  const float* A[3];
  const float* W[3];
  const float* Bv[3];
  const float* P[3];
  const float* Hb;
  const float* Zb;
  float* O[3];
  int n;
};

__device__ __forceinline__ void fma_tile(float (&acc)[4][4], const float* At,
                                         const float* Wt, int r0, int c0) {
#pragma unroll 4
  for (int k = 0; k < 64; ++k) {
    float4 a = *(const float4*)(At + k * 68 + r0);
    float4 w = *(const float4*)(Wt + k * 64 + c0);
    float av[4] = { a.x, a.y, a.z, a.w };
    float wv[4] = { w.x, w.y, w.z, w.w };
#pragma unroll
    for (int i = 0; i < 4; ++i)
#pragma unroll
      for (int j = 0; j < 4; ++j)
        acc[i][j] = fmaf(av[i], wv[j], acc[i][j]);
  }
}

template <int MODE, int G>
__global__ __launch_bounds__(256) void gemmf_kernel(FG p) {
  __shared__ float At[64 * 68];
  __shared__ float Wt[64 * 64];
  const int tid = threadIdx.x;
  const int n0 = blockIdx.x * 64;
  const int r0 = (tid >> 4) << 2;
  const int c0 = (tid & 15) << 2;
  float acc[G][4][4];
#pragma unroll
  for (int g = 0; g < G; ++g)
#pragma unroll
    for (int i = 0; i < 4; ++i)
#pragma unroll
      for (int j = 0; j < 4; ++j) acc[g][i][j] = 0.f;

  for (int kk = 0; kk < 3; ++kk) {
    const float* __restrict__ A = p.A[kk];
    __syncthreads();
#pragma unroll
    for (int j = 0; j < 4; ++j) {
      int flat = tid + 256 * j;
      int r = flat >> 4;
      int k4 = (flat & 15) << 2;
      int nn = n0 + r;
      float4 av = (nn < p.n) ? *(const float4*)(A + (size_t)nn * CH + k4)
                             : make_float4(0.f, 0.f, 0.f, 0.f);
      At[(k4 + 0) * 68 + r] = av.x;
      At[(k4 + 1) * 68 + r] = av.y;
      At[(k4 + 2) * 68 + r] = av.z;
      At[(k4 + 3) * 68 + r] = av.w;
    }
#pragma unroll
    for (int g = 0; g < G; ++g) {
      if (g > 0) __syncthreads();
      const float* __restrict__ Wk = p.W[g] + kk * 4096;
#pragma unroll
      for (int j = 0; j < 4; ++j) {
        int flat = tid + 256 * j;
        *(float4*)(Wt + flat * 4) = *(const float4*)(Wk + flat * 4);
      }
      __syncthreads();
      fma_tile(acc[g], At, Wt, r0, c0);
    }
  }

  if (MODE == 0) {
#pragma unroll
    for (int g = 0; g < G; ++g) {
      float4 bv = *(const float4*)(p.Bv[g] + c0);
#pragma unroll
      for (int i = 0; i < 4; ++i) {
        int nn = n0 + r0 + i;
        if (nn < p.n) {
          float4 o;
          o.x = acc[g][i][0] + bv.x;
          o.y = acc[g][i][1] + bv.y;
          o.z = acc[g][i][2] + bv.z;
          o.w = acc[g][i][3] + bv.w;
          *(float4*)(p.O[g] + (size_t)nn * CH + c0) = o;
        }
      }
    }
  } else if (MODE == 1) {
    float4 bz = *(const float4*)(p.Bv[0] + c0);
    float4 br = *(const float4*)(p.Bv[1] + c0);
#pragma unroll
    for (int i = 0; i < 4; ++i) {
      int nn = n0 + r0 + i;
      if (nn < p.n) {
        size_t idx = (size_t)nn * CH + c0;
        float4 pz = *(const float4*)(p.P[0] + idx);
        float4 pr = *(const float4*)(p.P[1] + idx);
        float4 h4 = *(const float4*)(p.Hb + idx);
        float4 z, gg;
        z.x = sigf(pz.x + bz.x + acc[0][i][0]);
        z.y = sigf(pz.y + bz.y + acc[0][i][1]);
        z.z = sigf(pz.z + bz.z + acc[0][i][2]);
        z.w = sigf(pz.w + bz.w + acc[0][i][3]);
        gg.x = h4.x * sigf(pr.x + br.x + acc[1][i][0]);
        gg.y = h4.y * sigf(pr.y + br.y + acc[1][i][1]);
        gg.z = h4.z * sigf(pr.z + br.z + acc[1][i][2]);
        gg.w = h4.w * sigf(pr.w + br.w + acc[1][i][3]);
        *(float4*)(p.O[0] + idx) = z;
        *(float4*)(p.O[1] + idx) = gg;
      }
    }
  } else {
    float4 bh = *(const float4*)(p.Bv[0] + c0);
#pragma unroll
    for (int i = 0; i < 4; ++i) {
      int nn = n0 + r0 + i;
      if (nn < p.n) {
        size_t idx = (size_t)nn * CH + c0;
        float4 ph = *(const float4*)(p.P[0] + idx);
        float4 z4 = *(const float4*)(p.Zb + idx);
        float4 h4 = *(const float4*)(p.Hb + idx);
        float4 o;
        float t0 = tanhf(ph.x + bh.x + acc[0][i][0]);
        float t1 = tanhf(ph.y + bh.y + acc[0][i][1]);
        float t2 = tanhf(ph.z + bh.z + acc[0][i][2]);
        float t3 = tanhf(ph.w + bh.w + acc[0][i][3]);
        o.x = z4.x * h4.x + (1.f - z4.x) * t0;
        o.y = z4.y * h4.y + (1.f - z4.y) * t1;
        o.z = z4.z * h4.z + (1.f - z4.z) * t2;
        o.w = z4.w * h4.w + (1.f - z4.w) * t3;
        *(float4*)(p.O[0] + idx) = o;
      }
    }
  }
}

// t=0 fallback: H=0 => out0 = (1-sig(xzp+b_hz)) * tanh(xhp+b_hh)
__global__ __launch_bounds__(256) void t0_kernel(
    const float4* __restrict__ xzp, const float4* __restrict__ xhp,
    const float* __restrict__ b_hz, const float* __restrict__ b_hh,
    float4* __restrict__ out0, ushort_t* __restrict__ out0b, int n4) {
  int i = blockIdx.x * 256 + threadIdx.x;
  if (i >= n4) return;
  int cb = (i << 2) & 63;
  float4 bz = *(const float4*)(b_hz + cb);
  float4 bh = *(const float4*)(b_hh + cb);
  float4 z4 = xzp[i], h4 = xhp[i];
  float4 o;
  o.x = (1.f - sigf(z4.x + bz.x)) * tanhf(h4.x + bh.x);
  o.y = (1.f - sigf(z4.y + bz.y)) * tanhf(h4.y + bh.y);
  o.z = (1.f - sigf(z4.z + bz.z)) * tanhf(h4.z + bh.z);
  o.w = (1.f - sigf(z4.w + bz.w)) * tanhf(h4.w + bh.w);
  out0[i] = o;
  if (out0b) {
    ushort4 ob;
    ob.x = f2bf(o.x); ob.y = f2bf(o.y); ob.z = f2bf(o.z); ob.w = f2bf(o.w);
    *(ushort4*)(out0b + (size_t)i * 4) = ob;
  }
}

extern "C" void kernel_launch(void* const* d_in, const int* in_sizes, int n_in,
                              void* d_out, int out_size, void* d_ws, size_t ws_size,
                              hipStream_t stream) {
  const float* X    = (const float*)d_in[0];
  const int*   ei   = (const int*)d_in[1];
  const float* ewt  = (const float*)d_in[2];
  const float* W_xz = (const float*)d_in[3];  const float* b_xz = (const float*)d_in[4];
  const float* W_hz = (const float*)d_in[5];  const float* b_hz = (const float*)d_in[6];
  const float* W_xr = (const float*)d_in[7];  const float* b_xr = (const float*)d_in[8];
  const float* W_hr = (const float*)d_in[9];  const float* b_hr = (const float*)d_in[10];
  const float* W_xh = (const float*)d_in[11]; const float* b_xh = (const float*)d_in[12];
  const float* W_hh = (const float*)d_in[13]; const float* b_hh = (const float*)d_in[14];

  const int N = in_sizes[0] / (SEQLEN * CH);
  const int E = in_sizes[1] / 2;
  const size_t NF = (size_t)N * CH;
  float* out = (float*)d_out;

  char* base = (char*)d_ws;
  size_t off = 0;
  auto take = [&](size_t bytes) -> void* {
    off = (off + 255) & ~(size_t)255;
    void* p = base + off;
    off += bytes;
    return p;
  };
  // --- fp32 core (needed by all tiers) ---
  float* deg   = (float*)take((size_t)N * 4);
  float* dinv  = (float*)take((size_t)N * 4);
  int*   cnt   = (int*)take((size_t)N * 4);
  int*   rowp  = (int*)take((size_t)(N + 1) * 4);
  int*   woff  = (int*)take((size_t)(N + 1) * 4);
  int*   bsum  = (int*)take(1024 * 4);
  int*   ccol  = (int*)take((size_t)E * 4);
  float* cwn   = (float*)take((size_t)E * 4);
  float* t1    = (float*)take(NF * 4);
  float* t2    = (float*)take(NF * 4);
  float* xz    = (float*)take(NF * 4);
  float* xr    = (float*)take(NF * 4);
  float* xh    = (float*)take(NF * 4);
  float* Gb    = (float*)take(NF * 4);
  // --- bf16 tier: transposed [node][slab][ch] bases + gather shadows + bf16 W^T ---
  ushort_t* Xb   = (ushort_t*)take(NF * 2 * SEQLEN);  // bf16(X), transposed
  ushort_t* t1xb = (ushort_t*)take(NF * 2 * SEQLEN);  // T1(X), transposed
  ushort_t* t2xb = (ushort_t*)take(NF * 2 * SEQLEN);  // T2(X), transposed
  ushort_t* Hbb  = (ushort_t*)take(NF * 2);
  ushort_t* Gbb  = (ushort_t*)take(NF * 2);
  ushort_t* t1b  = (ushort_t*)take(NF * 2);
  ushort_t* t2b  = (ushort_t*)take(NF * 2);
  ushort_t* Wxzb = (ushort_t*)take(3 * 4096 * 2);
  ushort_t* Wxrb = (ushort_t*)take(3 * 4096 * 2);
  ushort_t* Wxhb = (ushort_t*)take(3 * 4096 * 2);
  ushort_t* Whzb = (ushort_t*)take(3 * 4096 * 2);
  ushort_t* Whrb = (ushort_t*)take(3 * 4096 * 2);
  ushort_t* Whhb = (ushort_t*)take(3 * 4096 * 2);
  size_t off_bf = off;
  (void)n_in; (void)out_size;
  const bool useBF = (off_bf <= ws_size);

  hipMemsetAsync(deg, 0, (size_t)N * 4, stream);
  hipMemsetAsync(cnt, 0, (size_t)N * 4, stream);

  const int ebl = (E + 255) / 256;
  const int nbl = (N + 255) / 256;
  edge_hist_kernel<<<ebl, 256, 0, stream>>>(ei, ewt, deg, cnt, E);
  dinv_kernel<<<nbl, 256, 0, stream>>>(deg, dinv, N);
  scan_part_kernel<<<nbl, 256, 0, stream>>>(cnt, bsum, N);
  scan_top_kernel<<<1, 256, 0, stream>>>(bsum, nbl);
  scan_fill_kernel<<<nbl, 256, 0, stream>>>(cnt, bsum, rowp, woff, N, E);
  scatter_kernel<<<ebl, 256, 0, stream>>>(ei, ewt, dinv, woff, ccol, cwn, E);

  const int nq = (N + 3) / 4;
  const int g3x = (N + 63) / 64;
  const int gmx = (N + 127) / 128;
  const int n4 = (int)(NF / 4);
  const int ewbl = (n4 + 255) / 256;

  if (useBF) {
    // bf16 W^T conversions (tiny)
    cvt_wt_kernel<<<48, 256, 0, stream>>>(W_xz, Wxzb);
    cvt_wt_kernel<<<48, 256, 0, stream>>>(W_xr, Wxrb);
    cvt_wt_kernel<<<48, 256, 0, stream>>>(W_xh, Wxhb);
    cvt_wt_kernel<<<48, 256, 0, stream>>>(W_hz, Whzb);
    cvt_wt_kernel<<<48, 256, 0, stream>>>(W_hr, Whrb);
    cvt_wt_kernel<<<48, 256, 0, stream>>>(W_hh, Whhb);

    // Batched X-side Chebyshev bases over transposed layout.
    long long xn4 = (long long)(NF * SEQLEN / 4);
    cvt_bt_kernel<<<(int)((xn4 + 255) / 256), 256, 0, stream>>>(X, Xb, (long long)NF, xn4);
    spmv_bt_kernel<<<dim3(nq, 1), 256, 0, stream>>>(
        rowp, ccol, cwn, Xb, nullptr, t1xb, 1.f, 0.f, N, (long long)NF);
    spmv_bt_kernel<<<dim3(nq, 1), 256, 0, stream>>>(
        rowp, ccol, cwn, t1xb, X, t2xb, 2.f, -1.f, N, (long long)NF);

    for (int t = 0; t < SEQLEN; ++t) {
      float* outt = out + (size_t)t * NF;
      const ushort_t* Xs0 = Xb + (size_t)t * CH;
      const ushort_t* Xs1 = t1xb + (size_t)t * CH;
      const ushort_t* Xs2 = t2xb + (size_t)t * CH;

      if (t == 0) {
        // Fused t=0: gates (z,h), X side only; H-side contribution is bias-only.
        FGF p0 = {};
        p0.ABx[0] = Xs0; p0.ABx[1] = Xs1; p0.ABx[2] = Xs2;
        p0.WX[0] = Wxzb; p0.WX[1] = Wxhb;
        p0.BX[0] = b_xz; p0.BX[1] = b_xh;
        p0.BH[0] = b_hz; p0.BH[1] = b_hh;
        p0.O0 = outt; p0.OB = Hbb;
        p0.n = N;
        gemm_fused_kernel<0><<<dim3(gmx, 1, 1), 256, 0, stream>>>(p0);
        continue;
      }
      const float* H = out + (size_t)(t - 1) * NF;

      // H-side Chebyshev basis (bf16 gather -> bf16 shadows only; fp32 y dead)
      spmv_bfx_kernel<<<dim3(nq, 1), 256, 0, stream>>>(rowp, ccol, cwn, Hbb, H, nullptr, t1b, 1.f, 0.f, N);
      spmv_bfx_kernel<<<dim3(nq, 1), 256, 0, stream>>>(rowp, ccol, cwn, t1b, H, nullptr, t2b, 2.f, -1.f, N);

      // Fused (z,r): X-side + H-side MFMA, sigmoid, G = H*R
      FGF p1 = {};
      p1.ABx[0] = Xs0; p1.ABx[1] = Xs1; p1.ABx[2] = Xs2;
      p1.ABh[0] = Hbb; p1.ABh[1] = t1b; p1.ABh[2] = t2b;
      p1.WX[0] = Wxzb; p1.WX[1] = Wxrb;
      p1.WH[0] = Whzb; p1.WH[1] = Whrb;
      p1.BX[0] = b_xz; p1.BX[1] = b_xr;
      p1.BH[0] = b_hz; p1.BH[1] = b_hr;
      p1.Hb = H;
      p1.O0 = xz;   // Z
      p1.O1 = Gb;   // G = H*R (fp32, for t2 beta)
      p1.OB = Gbb;
      p1.n = N;
      gemm_fused_kernel<1><<<dim3(gmx, 1, 1), 256, 0, stream>>>(p1);

      // G-side Chebyshev basis
      spmv_bfx_kernel<<<dim3(nq, 1), 256, 0, stream>>>(rowp, ccol, cwn, Gbb, Gb, nullptr, t1b, 1.f, 0.f, N);
      spmv_bfx_kernel<<<dim3(nq, 1), 256, 0, stream>>>(rowp, ccol, cwn, t1b, Gb, nullptr, t2b, 2.f, -1.f, N);

      // Fused (h): X-side + G-side MFMA, tanh, GRU blend -> outt (+ bf16 H shadow)
      FGF p2 = {};
      p2.ABx[0] = Xs0; p2.ABx[1] = Xs1; p2.ABx[2] = Xs2;
      p2.ABh[0] = Gbb; p2.ABh[1] = t1b; p2.ABh[2] = t2b;
      p2.WX[0] = Wxhb;
      p2.WH[0] = Whhb;
      p2.BX[0] = b_xh;
      p2.BH[0] = b_hh;
      p2.Hb = H;
      p2.Zb = xz;
      p2.O0 = outt;
      p2.OB = (t < SEQLEN - 1) ? Hbb : nullptr;
      p2.n = N;
      gemm_fused_kernel<2><<<dim3(gmx, 1, 1), 256, 0, stream>>>(p2);
    }
  } else {
    // fp32 fallback (per-step everything, VALU GEMM)
    for (int t = 0; t < SEQLEN; ++t) {
      const float* Xt = X + (size_t)t * NF;
      float* outt = out + (size_t)t * NF;

      spmv_kernel<<<dim3(nq, 1), 256, 0, stream>>>(rowp, ccol, cwn, Xt, Xt, t1, 1.f, 0.f, N, 0);
      spmv_kernel<<<dim3(nq, 1), 256, 0, stream>>>(rowp, ccol, cwn, t1, Xt, t2, 2.f, -1.f, N, 0);
      FG px = {};
      px.A[0] = Xt; px.A[1] = t1; px.A[2] = t2;
      px.W[0] = W_xz; px.W[1] = W_xr; px.W[2] = W_xh;
      px.Bv[0] = b_xz; px.Bv[1] = b_xr; px.Bv[2] = b_xh;
      px.O[0] = xz; px.O[1] = xr; px.O[2] = xh;
      px.n = N;
      gemmf_kernel<0, 3><<<dim3(g3x, 1, 1), 256, 0, stream>>>(px);

      if (t == 0) {
        t0_kernel<<<ewbl, 256, 0, stream>>>((const float4*)xz, (const float4*)xh,
                                            b_hz, b_hh, (float4*)outt, nullptr, n4);
        continue;
      }
      const float* H = out + (size_t)(t - 1) * NF;

      spmv_kernel<<<dim3(nq, 1), 256, 0, stream>>>(rowp, ccol, cwn, H, H, t1, 1.f, 0.f, N, 0);
      spmv_kernel<<<dim3(nq, 1), 256, 0, stream>>>(rowp, ccol, cwn, t1, H, t2, 2.f, -1.f, N, 0);
      FG ph = {};
      ph.A[0] = H; ph.A[1] = t1; ph.A[2] = t2;
      ph.W[0] = W_hz; ph.W[1] = W_hr;
      ph.Bv[0] = b_hz; ph.Bv[1] = b_hr;
      ph.P[0] = xz; ph.P[1] = xr;
      ph.Hb = H;
      ph.O[0] = xz;
      ph.O[1] = Gb;
      ph.n = N;
      gemmf_kernel<1, 2><<<dim3(g3x, 1, 1), 256, 0, stream>>>(ph);

      spmv_kernel<<<dim3(nq, 1), 256, 0, stream>>>(rowp, ccol, cwn, Gb, Gb, t1, 1.f, 0.f, N, 0);
      spmv_kernel<<<dim3(nq, 1), 256, 0, stream>>>(rowp, ccol, cwn, t1, Gb, t2, 2.f, -1.f, N, 0);
      FG pg = {};
      pg.A[0] = Gb; pg.A[1] = t1; pg.A[2] = t2;
      pg.W[0] = W_hh;
      pg.Bv[0] = b_hh;
      pg.P[0] = xh;
      pg.Zb = xz;
      pg.Hb = H;
      pg.O[0] = outt;
      pg.n = N;
      gemmf_kernel<2, 1><<<dim3(g3x, 1, 1), 256, 0, stream>>>(pg);
    }
  }

  // Hlast = States[:, L-1]
  hipMemcpyAsync(out + (size_t)SEQLEN * NF, out + (size_t)(SEQLEN - 1) * NF,
                 NF * 4, hipMemcpyDeviceToDevice, stream);
}